// Round 4
// baseline (1828.531 us; speedup 1.0000x reference)
//
#include <hip/hip_runtime.h>

// HyMBA block, MI355X — ROUND 11: slim the GRU/SSM step critical path.
// (1) Broadcast-A: h replicated across all A rows => A-frag read is flat
//     H[p][c*32+quad*8], uniform per quad (4 addrs/wave, zero bank conflicts,
//     no [16][136] tile, no zero-fill, less addr VALU).
// (2) MFMA K-chain 4->2: accL (k<64) + accH (k>=64) parallel, add in epilogue.
// (3) v_cvt_pk_bf16_f32 packs both h bf16s in one instruction.
// Chunked LDS staging for ih/bx (R10) kept: loads have ~16 steps of slack.

#define MROWS 16384   // B*N rows
#define SEQ   2048
#define CH    16      // scan staging chunk (timesteps)
#define NCH   (SEQ / CH)

typedef __attribute__((ext_vector_type(8))) short bf16x8;
typedef __attribute__((ext_vector_type(4))) float f32x4;

__device__ __forceinline__ float bf2f(unsigned short u) {
    union { unsigned int i; float f; } c; c.i = ((unsigned int)u) << 16; return c.f;
}
__device__ __forceinline__ unsigned short f2bf(float f) {
    union { float f; unsigned int i; } c; c.f = f;
    unsigned int x = c.i;
    return (unsigned short)((x + 0x7fffu + ((x >> 16) & 1u)) >> 16);
}
// pack two f32 -> two bf16 (RNE) in one VALU instr
__device__ __forceinline__ unsigned int f2bf_pk(float lo, float hi) {
    unsigned int r;
    asm("v_cvt_pk_bf16_f32 %0, %1, %2" : "=v"(r) : "v"(lo), "v"(hi));
    return r;
}
__device__ __forceinline__ float ldin(const void* p, size_t i, int isf32) {
    return isf32 ? ((const float*)p)[i] : bf2f(((const unsigned short*)p)[i]);
}
__device__ __forceinline__ float sigf(float v) { return 1.f / (1.f + __expf(-v)); }
__device__ __forceinline__ float tanhf_fast(float v) { return 2.f * sigf(2.f * v) - 1.f; }

__global__ void sniff_kernel(const unsigned short* __restrict__ x, int* __restrict__ flag) {
    int tid = threadIdx.x;
    int big = 0;
    for (int i = tid; i < 1024; i += 64) {
        unsigned int e = (x[i] >> 7) & 0xFFu;
        big += (e >= 0xC0u) ? 1 : 0;
    }
#pragma unroll
    for (int off = 32; off; off >>= 1) big += __shfl_down(big, off);
    if (tid == 0) *flag = (big >= 4) ? 1 : 0;
}

__global__ void zero_out_kernel(float* __restrict__ out) {
    size_t i = ((size_t)blockIdx.x * 256 + threadIdx.x) * 16;
#pragma unroll
    for (int u = 0; u < 16; u++) out[i + u] = 0.f;
}

// ---------------- MFMA GEMM: 128x128 tile, BK=32, 256 threads ----------------
__device__ __forceinline__ void stage_tile(const void* __restrict__ g,
                                           int ld, int row0, int rowmax, int kb,
                                           short (*lds)[40], int tid, int isf32) {
#pragma unroll
    for (int q = 0; q < 2; q++) {
        int oct = q * 256 + tid;
        int row = oct >> 2, c8 = (oct & 3) << 3;
        int gr = row0 + row; if (gr > rowmax) gr = rowmax;
        size_t base = (size_t)gr * ld + kb + c8;
        bf16x8 v;
        if (isf32) {
            const float* gp = (const float*)g + base;
            float4 f0 = *reinterpret_cast<const float4*>(gp);
            float4 f1 = *reinterpret_cast<const float4*>(gp + 4);
            v[0] = (short)f2bf(f0.x); v[1] = (short)f2bf(f0.y);
            v[2] = (short)f2bf(f0.z); v[3] = (short)f2bf(f0.w);
            v[4] = (short)f2bf(f1.x); v[5] = (short)f2bf(f1.y);
            v[6] = (short)f2bf(f1.z); v[7] = (short)f2bf(f1.w);
        } else {
            v = *reinterpret_cast<const bf16x8*>((const unsigned short*)g + base);
        }
        *reinterpret_cast<bf16x8*>(&lds[row][c8]) = v;
    }
}

// A-frag: m=lane&15, k=(lane>>4)*8+j ; B-frag: n=lane&15 (W stored [n][k]).
// C/D: col=lane&15, row=(lane>>4)*4+reg   [m89-verified]
__device__ __forceinline__ void mfma_tiles(const short (*As)[40], const short (*Bs)[40],
                                           int wm, int wn, int lane, f32x4 (*acc)[4]) {
    bf16x8 af[4], bfr[4];
    int m = lane & 15, ko = (lane >> 4) << 3;
#pragma unroll
    for (int i = 0; i < 4; i++)
        af[i] = *reinterpret_cast<const bf16x8*>(&As[wm + i * 16 + m][ko]);
#pragma unroll
    for (int j = 0; j < 4; j++)
        bfr[j] = *reinterpret_cast<const bf16x8*>(&Bs[wn + j * 16 + m][ko]);
#pragma unroll
    for (int i = 0; i < 4; i++)
#pragma unroll
        for (int j = 0; j < 4; j++)
            acc[i][j] = __builtin_amdgcn_mfma_f32_16x16x32_bf16(af[i], bfr[j], acc[i][j], 0, 0, 0);
}

// C[M,N] = A[M,K]*W[N,K]^T + bias[N]; bf16 staging out
__global__ __launch_bounds__(256) void gemm_bt_kernel(
    const void* __restrict__ A, const void* __restrict__ W,
    const void* __restrict__ bias, unsigned short* __restrict__ C,
    int M, int N, int K, const int* __restrict__ flagp) {
    __shared__ __align__(16) short As[128][40];
    __shared__ __align__(16) short Bs[128][40];
    int isf32 = *flagp;
    int tid = threadIdx.x, lane = tid & 63, wave = tid >> 6;
    int wm = (wave >> 1) << 6, wn = (wave & 1) << 6;
    int tileM = blockIdx.x << 7, tileN = blockIdx.y << 7;
    f32x4 acc[4][4];
    f32x4 z = {0.f, 0.f, 0.f, 0.f};
#pragma unroll
    for (int i = 0; i < 4; i++)
#pragma unroll
        for (int j = 0; j < 4; j++) acc[i][j] = z;

    for (int kb = 0; kb < K; kb += 32) {
        __syncthreads();
        stage_tile(A, K, tileM, M - 1, kb, As, tid, isf32);
        stage_tile(W, K, tileN, N - 1, kb, Bs, tid, isf32);
        __syncthreads();
        mfma_tiles(As, Bs, wm, wn, lane, acc);
    }
#pragma unroll
    for (int i = 0; i < 4; i++) {
#pragma unroll
        for (int j = 0; j < 4; j++) {
            int col = tileN + wn + j * 16 + (lane & 15);
            if (col < N) {
                float bv = ldin(bias, col, isf32);
                int row0 = tileM + wm + i * 16 + ((lane >> 4) << 2);
#pragma unroll
                for (int r = 0; r < 4; r++)
                    C[(size_t)(row0 + r) * N + col] = f2bf(acc[i][j][r] + bv);
            }
        }
    }
}

// gx[row][2] = sigmoid(x_row . gate_w[g] + gate_b[g])
__global__ __launch_bounds__(256) void gate_kernel(
    const void* __restrict__ x, const void* __restrict__ gw,
    const void* __restrict__ gb, float* __restrict__ gx, const int* __restrict__ flagp) {
    int isf32 = *flagp;
    int row = (blockIdx.x << 2) + (threadIdx.x >> 6);
    int lane = threadIdx.x & 63;
    size_t xoff = (size_t)row * 1024 + lane * 16;
    float a0 = 0.f, a1 = 0.f;
#pragma unroll
    for (int q = 0; q < 2; q++) {
#pragma unroll
        for (int e = 0; e < 8; e++) {
            size_t k = q * 8 + e;
            float xf = ldin(x, xoff + k, isf32);
            a0 += xf * ldin(gw, (size_t)lane * 16 + k, isf32);
            a1 += xf * ldin(gw, 1024 + (size_t)lane * 16 + k, isf32);
        }
    }
#pragma unroll
    for (int off = 32; off > 0; off >>= 1) {
        a0 += __shfl_down(a0, off);
        a1 += __shfl_down(a1, off);
    }
    if (lane == 0) {
        gx[row * 2]     = sigf(a0 + ldin(gb, 0, isf32));
        gx[row * 2 + 1] = sigf(a1 + ldin(gb, 1, isf32));
    }
}

// ---------------- MFMA sequential scans ----------------
// blocks 0..7: GRU (batch b). 256 thr = 4 waves; wave w owns n-tiles {w+4l}.
// h kept as flat LDS row H[2][128] read broadcast-style by all A rows.
// ih staged in 16-step chunks into double-buffered LDS.
// blocks 8..15: SSM, wave 0 only, same structure, no barrier.
__global__ __launch_bounds__(256) void scan_kernel(
    const void* __restrict__ Amat,            // [64][64]
    const void* __restrict__ Whh,             // [384][128]
    const void* __restrict__ bhh,             // [384]
    const unsigned short* __restrict__ bxw,   // [MROWS][64]  bf16 (Bb included)
    const unsigned short* __restrict__ ihw,   // [MROWS][384] bf16 (b_ih included)
    unsigned short* __restrict__ hsw,         // [MROWS][64]
    unsigned short* __restrict__ hrw,         // [MROWS][128]
    const int* __restrict__ flagp) {
    int isf32 = *flagp;
    int b = blockIdx.x & 7;
    size_t rowbase = (size_t)b * SEQ;
    f32x4 zf = {0.f, 0.f, 0.f, 0.f};

    if (blockIdx.x < 8) {
        // ---------------- GRU ----------------
        __shared__ __align__(16) unsigned short H[2][128];       // flat h, dbuf
        __shared__ __align__(16) unsigned short IH[2][CH][384];  // ih chunk, dbuf (24.6KB)
        int tid = threadIdx.x, lane = tid & 63, w = tid >> 6;
        int col = lane & 15, quad = lane >> 4;
        ((unsigned short*)H)[tid] = 0;                           // 256 entries total
        // static B-fragments: Whh[n][k], n = (w+4l)*16+col, k = c*32+quad*8+e
        bf16x8 Bf[6][4];
#pragma unroll
        for (int l = 0; l < 6; l++) {
            int n = (w + 4 * l) * 16 + col;
#pragma unroll
            for (int c = 0; c < 4; c++) {
                int k0 = c * 32 + quad * 8;
                bf16x8 v;
#pragma unroll
                for (int e = 0; e < 8; e++)
                    v[e] = (short)f2bf(ldin(Whh, (size_t)n * 128 + k0 + e, isf32));
                Bf[l][c] = v;
            }
        }
        bool gl = (quad == 0);      // lanes 0-15 write h / hrw
        float bias_r[2], bias_z[2], bias_n[2], hprev[2];
#pragma unroll
        for (int p2 = 0; p2 < 2; p2++) {
            int o = (w + 4 * p2) * 16 + col;
            bias_r[p2] = ldin(bhh, o, isf32);
            bias_z[p2] = ldin(bhh, 128 + o, isf32);
            bias_n[p2] = ldin(bhh, 256 + o, isf32);
            hprev[p2] = 0.f;
        }
        // chunk prologue: chunk0 -> IH[0]; issue chunk1 loads
        const unsigned short* ihbase = ihw + rowbase * 384;
        bf16x8 stg[3];
#pragma unroll
        for (int q = 0; q < 3; q++)
            stg[q] = *reinterpret_cast<const bf16x8*>(ihbase + (size_t)(q * 256 + tid) * 8);
#pragma unroll
        for (int q = 0; q < 3; q++)
            *reinterpret_cast<bf16x8*>(&IH[0][0][0] + (size_t)(q * 256 + tid) * 8) = stg[q];
#pragma unroll
        for (int q = 0; q < 3; q++)
            stg[q] = *reinterpret_cast<const bf16x8*>(ihbase + (size_t)CH * 384 + (size_t)(q * 256 + tid) * 8);
        __syncthreads();

        int p = 0;
        for (int c = 0; c < NCH; c++) {
            int cur = c & 1;
            for (int tt = 0; tt < CH; tt++) {
                int t = c * CH + tt;
                // broadcast A-frags: uniform per quad (4 addrs/wave)
                bf16x8 Af[4];
#pragma unroll
                for (int cc = 0; cc < 4; cc++)
                    Af[cc] = *reinterpret_cast<const bf16x8*>(&H[p][cc * 32 + quad * 8]);
                float ir[2], iz[2], inn[2];
#pragma unroll
                for (int p2 = 0; p2 < 2; p2++) {
                    int o = (w + 4 * p2) * 16 + col;
                    ir[p2]  = bf2f(IH[cur][tt][o]);
                    iz[p2]  = bf2f(IH[cur][tt][128 + o]);
                    inn[p2] = bf2f(IH[cur][tt][256 + o]);
                }
                // two parallel 2-chains per output tile (K halves)
                f32x4 accL[6], accH[6];
#pragma unroll
                for (int l = 0; l < 6; l++) { accL[l] = zf; accH[l] = zf; }
#pragma unroll
                for (int l = 0; l < 6; l++) {
                    accL[l] = __builtin_amdgcn_mfma_f32_16x16x32_bf16(Af[0], Bf[l][0], accL[l], 0, 0, 0);
                    accH[l] = __builtin_amdgcn_mfma_f32_16x16x32_bf16(Af[2], Bf[l][2], accH[l], 0, 0, 0);
                    accL[l] = __builtin_amdgcn_mfma_f32_16x16x32_bf16(Af[1], Bf[l][1], accL[l], 0, 0, 0);
                    accH[l] = __builtin_amdgcn_mfma_f32_16x16x32_bf16(Af[3], Bf[l][3], accH[l], 0, 0, 0);
                }
                float hn[2];
#pragma unroll
                for (int p2 = 0; p2 < 2; p2++) {
                    float sr = accL[p2][0]     + accH[p2][0];
                    float sz = accL[2 + p2][0] + accH[2 + p2][0];
                    float sn = accL[4 + p2][0] + accH[4 + p2][0];
                    float r  = sigf(ir[p2]  + sr + bias_r[p2]);
                    float zg = sigf(iz[p2]  + sz + bias_z[p2]);
                    float n  = tanhf_fast(inn[p2] + r * (sn + bias_n[p2]));
                    float hnew = (1.f - zg) * n + zg * hprev[p2];
                    hprev[p2] = hnew;
                    hn[p2] = hnew;
                }
                unsigned int pk = f2bf_pk(hn[0], hn[1]);
                if (gl) {
                    int o0 = w * 16 + col;
                    H[p ^ 1][o0]      = (unsigned short)(pk & 0xFFFFu);
                    H[p ^ 1][o0 + 64] = (unsigned short)(pk >> 16);
                    hrw[(rowbase + t) * 128 + o0]      = (unsigned short)(pk & 0xFFFFu);
                    hrw[(rowbase + t) * 128 + o0 + 64] = (unsigned short)(pk >> 16);
                }
                asm volatile("s_waitcnt lgkmcnt(0)" ::: "memory");
                __builtin_amdgcn_s_barrier();
                asm volatile("" ::: "memory");
                p ^= 1;
            }
            if (c + 1 < NCH) {
                // write chunk c+1 (loaded ~CH steps ago), issue chunk c+2 loads
                unsigned short* dst = &IH[(c + 1) & 1][0][0];
#pragma unroll
                for (int q = 0; q < 3; q++)
                    *reinterpret_cast<bf16x8*>(dst + (size_t)(q * 256 + tid) * 8) = stg[q];
                if (c + 2 < NCH) {
#pragma unroll
                    for (int q = 0; q < 3; q++)
                        stg[q] = *reinterpret_cast<const bf16x8*>(
                            ihbase + (size_t)(c + 2) * CH * 384 + (size_t)(q * 256 + tid) * 8);
                }
                asm volatile("s_waitcnt lgkmcnt(0)" ::: "memory");
                __builtin_amdgcn_s_barrier();
                asm volatile("" ::: "memory");
            }
        }
    } else {
        // ---------------- SSM (wave 0 only) ----------------
        if (threadIdx.x >= 64) return;
        int lane = threadIdx.x, col = lane & 15, quad = lane >> 4;
        __shared__ __align__(16) unsigned short Hs[2][64];       // flat h, dbuf
        __shared__ __align__(16) unsigned short BX[2][CH][64];   // bx chunk, dbuf (4KB)
        ((unsigned short*)Hs)[lane] = 0;
        ((unsigned short*)Hs)[64 + lane] = 0;
        bf16x8 Bf[4][2];
#pragma unroll
        for (int l = 0; l < 4; l++) {
            int n = l * 16 + col;
#pragma unroll
            for (int c = 0; c < 2; c++) {
                int k0 = c * 32 + quad * 8;
                bf16x8 v;
#pragma unroll
                for (int e = 0; e < 8; e++)
                    v[e] = (short)f2bf(ldin(Amat, (size_t)n * 64 + k0 + e, isf32));
                Bf[l][c] = v;
            }
        }
        bool gl = (quad == 0);
        const unsigned short* bxbase = bxw + rowbase * 64;
        bf16x8 stg[2];
#pragma unroll
        for (int q = 0; q < 2; q++)
            stg[q] = *reinterpret_cast<const bf16x8*>(bxbase + (size_t)(q * 64 + lane) * 8);
#pragma unroll
        for (int q = 0; q < 2; q++)
            *reinterpret_cast<bf16x8*>(&BX[0][0][0] + (size_t)(q * 64 + lane) * 8) = stg[q];
#pragma unroll
        for (int q = 0; q < 2; q++)
            stg[q] = *reinterpret_cast<const bf16x8*>(bxbase + (size_t)CH * 64 + (size_t)(q * 64 + lane) * 8);
        asm volatile("s_waitcnt lgkmcnt(0)" ::: "memory");

        int p = 0;
        for (int c = 0; c < NCH; c++) {
            int cur = c & 1;
            for (int tt = 0; tt < CH; tt++) {
                int t = c * CH + tt;
                bf16x8 Af[2];
#pragma unroll
                for (int cc = 0; cc < 2; cc++)
                    Af[cc] = *reinterpret_cast<const bf16x8*>(&Hs[p][cc * 32 + quad * 8]);
                float bx[4];
#pragma unroll
                for (int l = 0; l < 4; l++) bx[l] = bf2f(BX[cur][tt][l * 16 + col]);
                f32x4 acc[4];
#pragma unroll
                for (int l = 0; l < 4; l++) acc[l] = zf;
#pragma unroll
                for (int l = 0; l < 4; l++)
#pragma unroll
                    for (int cc = 0; cc < 2; cc++)
                        acc[l] = __builtin_amdgcn_mfma_f32_16x16x32_bf16(Af[cc], Bf[l][cc], acc[l], 0, 0, 0);
#pragma unroll
                for (int l = 0; l < 4; l++) {
                    int o = l * 16 + col;
                    float v = acc[l][0] + bx[l];
                    float hv = v * sigf(v);
                    unsigned short hb = f2bf(hv);
                    if (gl) {
                        Hs[p ^ 1][o] = hb;
                        hsw[(rowbase + t) * 64 + o] = hb;
                    }
                }
                asm volatile("s_waitcnt lgkmcnt(0)" ::: "memory");
                p ^= 1;
            }
            if (c + 1 < NCH) {
                unsigned short* dst = &BX[(c + 1) & 1][0][0];
#pragma unroll
                for (int q = 0; q < 2; q++)
                    *reinterpret_cast<bf16x8*>(dst + (size_t)(q * 64 + lane) * 8) = stg[q];
                if (c + 2 < NCH) {
#pragma unroll
                    for (int q = 0; q < 2; q++)
                        stg[q] = *reinterpret_cast<const bf16x8*>(
                            bxbase + (size_t)(c + 2) * CH * 64 + (size_t)(q * 64 + lane) * 8);
                }
                asm volatile("s_waitcnt lgkmcnt(0)" ::: "memory");
            }
        }
    }
}

// out[row,col] = g0*(x.Dw^T + hs.Cw^T + Cb + Db) + g1*(hr.pw^T + pb) — f32 store
__global__ __launch_bounds__(256) void out_kernel(
    const void* __restrict__ x,  const void* __restrict__ Dw, const void* __restrict__ Db,
    const unsigned short* __restrict__ hs, const void* __restrict__ Cw, const void* __restrict__ Cb,
    const unsigned short* __restrict__ hr, const void* __restrict__ pw, const void* __restrict__ pb,
    const float* __restrict__ gx, float* __restrict__ out,
    const int* __restrict__ flagp) {
    __shared__ __align__(16) short As[128][40];
    __shared__ __align__(16) short Bs[128][40];
    int isf32 = *flagp;
    int tid = threadIdx.x, lane = tid & 63, wave = tid >> 6;
    int wm = (wave >> 1) << 6, wn = (wave & 1) << 6;
    int tileM = blockIdx.x << 7, tileN = blockIdx.y << 7;
    f32x4 z = {0.f, 0.f, 0.f, 0.f};
    f32x4 acc1[4][4], acc2[4][4];
#pragma unroll
    for (int i = 0; i < 4; i++)
#pragma unroll
        for (int j = 0; j < 4; j++) { acc1[i][j] = z; acc2[i][j] = z; }

    for (int kb = 0; kb < 1024; kb += 32) {        // x . Dw^T
        __syncthreads();
        stage_tile(x,  1024, tileM, MROWS - 1, kb, As, tid, isf32);
        stage_tile(Dw, 1024, tileN, 1023, kb, Bs, tid, isf32);
        __syncthreads();
        mfma_tiles(As, Bs, wm, wn, lane, acc1);
    }
    for (int kb = 0; kb < 64; kb += 32) {          // + hs . Cw^T, same acc
        __syncthreads();
        stage_tile(hs, 64, tileM, MROWS - 1, kb, As, tid, 0);
        stage_tile(Cw, 64, tileN, 1023, kb, Bs, tid, isf32);
        __syncthreads();
        mfma_tiles(As, Bs, wm, wn, lane, acc1);
    }
    for (int kb = 0; kb < 128; kb += 32) {         // hr . pw^T
        __syncthreads();
        stage_tile(hr, 128, tileM, MROWS - 1, kb, As, tid, 0);
        stage_tile(pw, 128, tileN, 1023, kb, Bs, tid, isf32);
        __syncthreads();
        mfma_tiles(As, Bs, wm, wn, lane, acc2);
    }
#pragma unroll
    for (int i = 0; i < 4; i++) {
        int r0 = tileM + wm + i * 16 + ((lane >> 4) << 2);
#pragma unroll
        for (int j = 0; j < 4; j++) {
            int col = tileN + wn + j * 16 + (lane & 15);
            float cb  = ldin(Cb, col, isf32) + ldin(Db, col, isf32);
            float pbv = ldin(pb, col, isf32);
#pragma unroll
            for (int r = 0; r < 4; r++) {
                int row = r0 + r;
                float g0 = gx[row * 2], g1 = gx[row * 2 + 1];
                out[(size_t)row * 1024 + col] =
                    g0 * (acc1[i][j][r] + cb) + g1 * (acc2[i][j][r] + pbv);
            }
        }
    }
}

extern "C" void kernel_launch(void* const* d_in, const int* in_sizes, int n_in,
                              void* d_out, int out_size, void* d_ws, size_t ws_size,
                              hipStream_t stream) {
    static const int expect_sizes[16] = {16777216, 4096, 65536, 64, 65536, 1024,
                                         1048576, 1024, 393216, 384, 49152, 384,
                                         131072, 1024, 2048, 2};
    bool order_ok = (n_in == 16);
    if (order_ok)
        for (int i = 0; i < 16; i++)
            if (in_sizes[i] != expect_sizes[i]) { order_ok = false; break; }
    float* out = (float*)d_out;
    if (!order_ok) {
        zero_out_kernel<<<dim3(4096), dim3(256), 0, stream>>>(out);
        return;
    }

    const void* x    = d_in[0];
    const void* Amat = d_in[1];
    const void* Bw   = d_in[2];
    const void* Bb   = d_in[3];
    const void* Cw   = d_in[4];
    const void* Cb   = d_in[5];
    const void* Dw   = d_in[6];
    const void* Db   = d_in[7];
    const void* Wih  = d_in[8];
    const void* bih  = d_in[9];
    const void* Whh  = d_in[10];
    const void* bhh  = d_in[11];
    const void* pw   = d_in[12];
    const void* pb   = d_in[13];
    const void* gw   = d_in[14];
    const void* gb   = d_in[15];

    // d_ws (21.1 MB): flag | gx | hs | hr | bx | ih
    char* ws = (char*)d_ws;
    int*            flg = (int*)(ws);                        //       256 B
    float*          gxw = (float*)(ws + 256);                //   131,072 B
    unsigned short* hsw = (unsigned short*)(ws + 131328);    // 2,097,152 B
    unsigned short* hrw = (unsigned short*)(ws + 2228480);   // 4,194,304 B
    unsigned short* bxw = (unsigned short*)(ws + 6422784);   // 2,097,152 B
    unsigned short* ihw = (unsigned short*)(ws + 8519936);   // 12,582,912 B

    dim3 blk(256);
    sniff_kernel<<<dim3(1), dim3(64), 0, stream>>>((const unsigned short*)x, flg);
    gemm_bt_kernel<<<dim3(128, 3), blk, 0, stream>>>(x, Wih, bih, ihw, MROWS, 384, 1024, flg);
    gemm_bt_kernel<<<dim3(128, 1), blk, 0, stream>>>(x, Bw, Bb, bxw, MROWS, 64, 1024, flg);
    gate_kernel<<<dim3(4096), blk, 0, stream>>>(x, gw, gb, gxw, flg);
    scan_kernel<<<dim3(16), blk, 0, stream>>>(Amat, Whh, bhh, bxw, ihw, hsw, hrw, flg);
    out_kernel<<<dim3(128, 8), blk, 0, stream>>>(x, Dw, Db, hsw, Cw, Cb, hrw, pw, pb, gxw, out, flg);
}

// Round 5
// 1523.077 us; speedup vs baseline: 1.2006x; 1.2006x over previous
//
#include <hip/hip_runtime.h>

// HyMBA block, MI355X — ROUND 12: 8-wave GRU (2 waves/SIMD latency hiding).
// R11 post-mortem: bank conflicts -> 0 with zero time delta => step is a
// serial latency chain (1 wave/SIMD, no TLP). Fix: 512-thread GRU blocks,
// wave w owns the (r,z,n) tile triple for cols [16w,16w+16); 12 MFMA/wave.
// Two waves per SIMD interleave: one wave's ds_read/MFMA-latency/tanh chain
// hides under the other's issue. Also: v_cvt_pk_bf16_f32 replaces manual
// f2bf bit-twiddling in GEMM staging + epilogue (6 ops -> 0.5 ops/elem).

#define MROWS 16384   // B*N rows
#define SEQ   2048
#define CH    16      // scan staging chunk (timesteps)
#define NCH   (SEQ / CH)

typedef __attribute__((ext_vector_type(8))) short bf16x8;
typedef __attribute__((ext_vector_type(4))) float f32x4;

__device__ __forceinline__ float bf2f(unsigned short u) {
    union { unsigned int i; float f; } c; c.i = ((unsigned int)u) << 16; return c.f;
}
__device__ __forceinline__ unsigned short f2bf(float f) {
    union { float f; unsigned int i; } c; c.f = f;
    unsigned int x = c.i;
    return (unsigned short)((x + 0x7fffu + ((x >> 16) & 1u)) >> 16);
}
// pack two f32 -> two bf16 (RNE) in one VALU instr
__device__ __forceinline__ unsigned int f2bf_pk(float lo, float hi) {
    unsigned int r;
    asm("v_cvt_pk_bf16_f32 %0, %1, %2" : "=v"(r) : "v"(lo), "v"(hi));
    return r;
}
__device__ __forceinline__ float ldin(const void* p, size_t i, int isf32) {
    return isf32 ? ((const float*)p)[i] : bf2f(((const unsigned short*)p)[i]);
}
__device__ __forceinline__ float sigf(float v) { return 1.f / (1.f + __expf(-v)); }
__device__ __forceinline__ float tanhf_fast(float v) { return 2.f * sigf(2.f * v) - 1.f; }

__global__ void sniff_kernel(const unsigned short* __restrict__ x, int* __restrict__ flag) {
    int tid = threadIdx.x;
    int big = 0;
    for (int i = tid; i < 1024; i += 64) {
        unsigned int e = (x[i] >> 7) & 0xFFu;
        big += (e >= 0xC0u) ? 1 : 0;
    }
#pragma unroll
    for (int off = 32; off; off >>= 1) big += __shfl_down(big, off);
    if (tid == 0) *flag = (big >= 4) ? 1 : 0;
}

__global__ void zero_out_kernel(float* __restrict__ out) {
    size_t i = ((size_t)blockIdx.x * 256 + threadIdx.x) * 16;
#pragma unroll
    for (int u = 0; u < 16; u++) out[i + u] = 0.f;
}

// ---------------- MFMA GEMM: 128x128 tile, BK=32, 256 threads ----------------
__device__ __forceinline__ void stage_tile(const void* __restrict__ g,
                                           int ld, int row0, int rowmax, int kb,
                                           short (*lds)[40], int tid, int isf32) {
#pragma unroll
    for (int q = 0; q < 2; q++) {
        int oct = q * 256 + tid;
        int row = oct >> 2, c8 = (oct & 3) << 3;
        int gr = row0 + row; if (gr > rowmax) gr = rowmax;
        size_t base = (size_t)gr * ld + kb + c8;
        bf16x8 v;
        if (isf32) {
            const float* gp = (const float*)g + base;
            float4 f0 = *reinterpret_cast<const float4*>(gp);
            float4 f1 = *reinterpret_cast<const float4*>(gp + 4);
            union { bf16x8 v8; unsigned int u[4]; } u;
            u.u[0] = f2bf_pk(f0.x, f0.y);
            u.u[1] = f2bf_pk(f0.z, f0.w);
            u.u[2] = f2bf_pk(f1.x, f1.y);
            u.u[3] = f2bf_pk(f1.z, f1.w);
            v = u.v8;
        } else {
            v = *reinterpret_cast<const bf16x8*>((const unsigned short*)g + base);
        }
        *reinterpret_cast<bf16x8*>(&lds[row][c8]) = v;
    }
}

// A-frag: m=lane&15, k=(lane>>4)*8+j ; B-frag: n=lane&15 (W stored [n][k]).
// C/D: col=lane&15, row=(lane>>4)*4+reg   [m89-verified]
__device__ __forceinline__ void mfma_tiles(const short (*As)[40], const short (*Bs)[40],
                                           int wm, int wn, int lane, f32x4 (*acc)[4]) {
    bf16x8 af[4], bfr[4];
    int m = lane & 15, ko = (lane >> 4) << 3;
#pragma unroll
    for (int i = 0; i < 4; i++)
        af[i] = *reinterpret_cast<const bf16x8*>(&As[wm + i * 16 + m][ko]);
#pragma unroll
    for (int j = 0; j < 4; j++)
        bfr[j] = *reinterpret_cast<const bf16x8*>(&Bs[wn + j * 16 + m][ko]);
#pragma unroll
    for (int i = 0; i < 4; i++)
#pragma unroll
        for (int j = 0; j < 4; j++)
            acc[i][j] = __builtin_amdgcn_mfma_f32_16x16x32_bf16(af[i], bfr[j], acc[i][j], 0, 0, 0);
}

// C[M,N] = A[M,K]*W[N,K]^T + bias[N]; bf16 staging out
__global__ __launch_bounds__(256) void gemm_bt_kernel(
    const void* __restrict__ A, const void* __restrict__ W,
    const void* __restrict__ bias, unsigned short* __restrict__ C,
    int M, int N, int K, const int* __restrict__ flagp) {
    __shared__ __align__(16) short As[128][40];
    __shared__ __align__(16) short Bs[128][40];
    int isf32 = *flagp;
    int tid = threadIdx.x, lane = tid & 63, wave = tid >> 6;
    int wm = (wave >> 1) << 6, wn = (wave & 1) << 6;
    int tileM = blockIdx.x << 7, tileN = blockIdx.y << 7;
    f32x4 acc[4][4];
    f32x4 z = {0.f, 0.f, 0.f, 0.f};
#pragma unroll
    for (int i = 0; i < 4; i++)
#pragma unroll
        for (int j = 0; j < 4; j++) acc[i][j] = z;

    for (int kb = 0; kb < K; kb += 32) {
        __syncthreads();
        stage_tile(A, K, tileM, M - 1, kb, As, tid, isf32);
        stage_tile(W, K, tileN, N - 1, kb, Bs, tid, isf32);
        __syncthreads();
        mfma_tiles(As, Bs, wm, wn, lane, acc);
    }
#pragma unroll
    for (int i = 0; i < 4; i++) {
#pragma unroll
        for (int j = 0; j < 4; j++) {
            int col = tileN + wn + j * 16 + (lane & 15);
            if (col < N) {
                float bv = ldin(bias, col, isf32);
                int row0 = tileM + wm + i * 16 + ((lane >> 4) << 2);
                unsigned int pk0 = f2bf_pk(acc[i][j][0] + bv, acc[i][j][1] + bv);
                unsigned int pk1 = f2bf_pk(acc[i][j][2] + bv, acc[i][j][3] + bv);
                C[(size_t)(row0 + 0) * N + col] = (unsigned short)(pk0 & 0xFFFFu);
                C[(size_t)(row0 + 1) * N + col] = (unsigned short)(pk0 >> 16);
                C[(size_t)(row0 + 2) * N + col] = (unsigned short)(pk1 & 0xFFFFu);
                C[(size_t)(row0 + 3) * N + col] = (unsigned short)(pk1 >> 16);
            }
        }
    }
}

// gx[row][2] = sigmoid(x_row . gate_w[g] + gate_b[g])
__global__ __launch_bounds__(256) void gate_kernel(
    const void* __restrict__ x, const void* __restrict__ gw,
    const void* __restrict__ gb, float* __restrict__ gx, const int* __restrict__ flagp) {
    int isf32 = *flagp;
    int row = (blockIdx.x << 2) + (threadIdx.x >> 6);
    int lane = threadIdx.x & 63;
    size_t xoff = (size_t)row * 1024 + lane * 16;
    float a0 = 0.f, a1 = 0.f;
#pragma unroll
    for (int q = 0; q < 2; q++) {
#pragma unroll
        for (int e = 0; e < 8; e++) {
            size_t k = q * 8 + e;
            float xf = ldin(x, xoff + k, isf32);
            a0 += xf * ldin(gw, (size_t)lane * 16 + k, isf32);
            a1 += xf * ldin(gw, 1024 + (size_t)lane * 16 + k, isf32);
        }
    }
#pragma unroll
    for (int off = 32; off > 0; off >>= 1) {
        a0 += __shfl_down(a0, off);
        a1 += __shfl_down(a1, off);
    }
    if (lane == 0) {
        gx[row * 2]     = sigf(a0 + ldin(gb, 0, isf32));
        gx[row * 2 + 1] = sigf(a1 + ldin(gb, 1, isf32));
    }
}

// ---------------- MFMA sequential scans ----------------
// blocks 0..7: GRU (batch b). 512 thr = 8 waves (2/SIMD); wave w owns the
// r/z/n tile triple for cols [16w, 16w+16). 12 MFMA/wave/step. h broadcast
// via flat LDS row H[2][128]. ih staged in 16-step LDS chunks (dbuf).
// blocks 8..15: SSM, wave 0 only, unchanged.
__global__ __launch_bounds__(512) void scan_kernel(
    const void* __restrict__ Amat,            // [64][64]
    const void* __restrict__ Whh,             // [384][128]
    const void* __restrict__ bhh,             // [384]
    const unsigned short* __restrict__ bxw,   // [MROWS][64]  bf16 (Bb included)
    const unsigned short* __restrict__ ihw,   // [MROWS][384] bf16 (b_ih included)
    unsigned short* __restrict__ hsw,         // [MROWS][64]
    unsigned short* __restrict__ hrw,         // [MROWS][128]
    const int* __restrict__ flagp) {
    int isf32 = *flagp;
    int b = blockIdx.x & 7;
    size_t rowbase = (size_t)b * SEQ;
    f32x4 zf = {0.f, 0.f, 0.f, 0.f};

    if (blockIdx.x < 8) {
        // ---------------- GRU (8 waves) ----------------
        __shared__ __align__(16) unsigned short H[2][128];       // flat h, dbuf
        __shared__ __align__(16) unsigned short IH[2][CH][384];  // ih chunk, dbuf (24.6KB)
        int tid = threadIdx.x, lane = tid & 63, w = tid >> 6;    // w in 0..7
        int col = lane & 15, quad = lane >> 4;
        int o = w * 16 + col;                                    // this wave's col
        if (tid < 256) ((unsigned short*)H)[tid] = 0;
        // static B-fragments: g=0(r),1(z),2(n): Whh row g*128+o, k = c*32+quad*8+e
        bf16x8 Bf[3][4];
#pragma unroll
        for (int g = 0; g < 3; g++) {
            int n = g * 128 + o;
#pragma unroll
            for (int c = 0; c < 4; c++) {
                int k0 = c * 32 + quad * 8;
                bf16x8 v;
#pragma unroll
                for (int e = 0; e < 8; e++)
                    v[e] = (short)f2bf(ldin(Whh, (size_t)n * 128 + k0 + e, isf32));
                Bf[g][c] = v;
            }
        }
        float bias_r = ldin(bhh, o, isf32);
        float bias_z = ldin(bhh, 128 + o, isf32);
        float bias_n = ldin(bhh, 256 + o, isf32);
        float hprev = 0.f;
        bool gl = (quad == 0);
        // chunk prologue: chunk0 -> IH[0]; issue chunk1 loads (768 bf16x8/chunk)
        const unsigned short* ihbase = ihw + rowbase * 384;
        bf16x8 stg0, stg1;
        stg0 = *reinterpret_cast<const bf16x8*>(ihbase + (size_t)tid * 8);
        if (tid < 256) stg1 = *reinterpret_cast<const bf16x8*>(ihbase + (size_t)(512 + tid) * 8);
        *reinterpret_cast<bf16x8*>(&IH[0][0][0] + (size_t)tid * 8) = stg0;
        if (tid < 256) *reinterpret_cast<bf16x8*>(&IH[0][0][0] + (size_t)(512 + tid) * 8) = stg1;
        stg0 = *reinterpret_cast<const bf16x8*>(ihbase + (size_t)CH * 384 + (size_t)tid * 8);
        if (tid < 256) stg1 = *reinterpret_cast<const bf16x8*>(ihbase + (size_t)CH * 384 + (size_t)(512 + tid) * 8);
        __syncthreads();

        int p = 0;
        for (int c = 0; c < NCH; c++) {
            int cur = c & 1;
            for (int tt = 0; tt < CH; tt++) {
                int t = c * CH + tt;
                // broadcast A-frags: uniform per quad (4 addrs/wave)
                bf16x8 Af[4];
#pragma unroll
                for (int cc = 0; cc < 4; cc++)
                    Af[cc] = *reinterpret_cast<const bf16x8*>(&H[p][cc * 32 + quad * 8]);
                float ir  = bf2f(IH[cur][tt][o]);
                float iz  = bf2f(IH[cur][tt][128 + o]);
                float inn = bf2f(IH[cur][tt][256 + o]);
                // 3 gates x two parallel 2-chains (K halves)
                f32x4 accL[3], accH[3];
#pragma unroll
                for (int g = 0; g < 3; g++) { accL[g] = zf; accH[g] = zf; }
#pragma unroll
                for (int g = 0; g < 3; g++) {
                    accL[g] = __builtin_amdgcn_mfma_f32_16x16x32_bf16(Af[0], Bf[g][0], accL[g], 0, 0, 0);
                    accH[g] = __builtin_amdgcn_mfma_f32_16x16x32_bf16(Af[2], Bf[g][2], accH[g], 0, 0, 0);
                    accL[g] = __builtin_amdgcn_mfma_f32_16x16x32_bf16(Af[1], Bf[g][1], accL[g], 0, 0, 0);
                    accH[g] = __builtin_amdgcn_mfma_f32_16x16x32_bf16(Af[3], Bf[g][3], accH[g], 0, 0, 0);
                }
                float sr = accL[0][0] + accH[0][0];
                float sz = accL[1][0] + accH[1][0];
                float sn = accL[2][0] + accH[2][0];
                float r  = sigf(ir + sr + bias_r);
                float zg = sigf(iz + sz + bias_z);
                float n  = tanhf_fast(inn + r * (sn + bias_n));
                float hnew = (1.f - zg) * n + zg * hprev;
                hprev = hnew;
                if (gl) {
                    unsigned short hb = f2bf(hnew);
                    H[p ^ 1][o] = hb;
                    hrw[(rowbase + t) * 128 + o] = hb;
                }
                asm volatile("s_waitcnt lgkmcnt(0)" ::: "memory");
                __builtin_amdgcn_s_barrier();
                asm volatile("" ::: "memory");
                p ^= 1;
            }
            if (c + 1 < NCH) {
                // write chunk c+1 (loaded ~CH steps ago), issue chunk c+2 loads
                unsigned short* dst = &IH[(c + 1) & 1][0][0];
                *reinterpret_cast<bf16x8*>(dst + (size_t)tid * 8) = stg0;
                if (tid < 256) *reinterpret_cast<bf16x8*>(dst + (size_t)(512 + tid) * 8) = stg1;
                if (c + 2 < NCH) {
                    const unsigned short* src = ihbase + (size_t)(c + 2) * CH * 384;
                    stg0 = *reinterpret_cast<const bf16x8*>(src + (size_t)tid * 8);
                    if (tid < 256) stg1 = *reinterpret_cast<const bf16x8*>(src + (size_t)(512 + tid) * 8);
                }
                asm volatile("s_waitcnt lgkmcnt(0)" ::: "memory");
                __builtin_amdgcn_s_barrier();
                asm volatile("" ::: "memory");
            }
        }
    } else {
        // ---------------- SSM (wave 0 only) ----------------
        if (threadIdx.x >= 64) return;
        int lane = threadIdx.x, col = lane & 15, quad = lane >> 4;
        __shared__ __align__(16) unsigned short Hs[2][64];       // flat h, dbuf
        __shared__ __align__(16) unsigned short BX[2][CH][64];   // bx chunk, dbuf (4KB)
        ((unsigned short*)Hs)[lane] = 0;
        ((unsigned short*)Hs)[64 + lane] = 0;
        bf16x8 Bf[4][2];
#pragma unroll
        for (int l = 0; l < 4; l++) {
            int n = l * 16 + col;
#pragma unroll
            for (int c = 0; c < 2; c++) {
                int k0 = c * 32 + quad * 8;
                bf16x8 v;
#pragma unroll
                for (int e = 0; e < 8; e++)
                    v[e] = (short)f2bf(ldin(Amat, (size_t)n * 64 + k0 + e, isf32));
                Bf[l][c] = v;
            }
        }
        bool gl = (quad == 0);
        const unsigned short* bxbase = bxw + rowbase * 64;
        bf16x8 stg[2];
#pragma unroll
        for (int q = 0; q < 2; q++)
            stg[q] = *reinterpret_cast<const bf16x8*>(bxbase + (size_t)(q * 64 + lane) * 8);
#pragma unroll
        for (int q = 0; q < 2; q++)
            *reinterpret_cast<bf16x8*>(&BX[0][0][0] + (size_t)(q * 64 + lane) * 8) = stg[q];
#pragma unroll
        for (int q = 0; q < 2; q++)
            stg[q] = *reinterpret_cast<const bf16x8*>(bxbase + (size_t)CH * 64 + (size_t)(q * 64 + lane) * 8);
        asm volatile("s_waitcnt lgkmcnt(0)" ::: "memory");

        int p = 0;
        for (int c = 0; c < NCH; c++) {
            int cur = c & 1;
            for (int tt = 0; tt < CH; tt++) {
                int t = c * CH + tt;
                bf16x8 Af[2];
#pragma unroll
                for (int cc = 0; cc < 2; cc++)
                    Af[cc] = *reinterpret_cast<const bf16x8*>(&Hs[p][cc * 32 + quad * 8]);
                float bx[4];
#pragma unroll
                for (int l = 0; l < 4; l++) bx[l] = bf2f(BX[cur][tt][l * 16 + col]);
                f32x4 acc[4];
#pragma unroll
                for (int l = 0; l < 4; l++) acc[l] = zf;
#pragma unroll
                for (int l = 0; l < 4; l++)
#pragma unroll
                    for (int cc = 0; cc < 2; cc++)
                        acc[l] = __builtin_amdgcn_mfma_f32_16x16x32_bf16(Af[cc], Bf[l][cc], acc[l], 0, 0, 0);
#pragma unroll
                for (int l = 0; l < 4; l++) {
                    int o = l * 16 + col;
                    float v = acc[l][0] + bx[l];
                    float hv = v * sigf(v);
                    unsigned short hb = f2bf(hv);
                    if (gl) {
                        Hs[p ^ 1][o] = hb;
                        hsw[(rowbase + t) * 64 + o] = hb;
                    }
                }
                asm volatile("s_waitcnt lgkmcnt(0)" ::: "memory");
                p ^= 1;
            }
            if (c + 1 < NCH) {
                unsigned short* dst = &BX[(c + 1) & 1][0][0];
#pragma unroll
                for (int q = 0; q < 2; q++)
                    *reinterpret_cast<bf16x8*>(dst + (size_t)(q * 64 + lane) * 8) = stg[q];
                if (c + 2 < NCH) {
#pragma unroll
                    for (int q = 0; q < 2; q++)
                        stg[q] = *reinterpret_cast<const bf16x8*>(
                            bxbase + (size_t)(c + 2) * CH * 64 + (size_t)(q * 64 + lane) * 8);
                }
                asm volatile("s_waitcnt lgkmcnt(0)" ::: "memory");
            }
        }
    }
}

// out[row,col] = g0*(x.Dw^T + hs.Cw^T + Cb + Db) + g1*(hr.pw^T + pb) — f32 store
__global__ __launch_bounds__(256) void out_kernel(
    const void* __restrict__ x,  const void* __restrict__ Dw, const void* __restrict__ Db,
    const unsigned short* __restrict__ hs, const void* __restrict__ Cw, const void* __restrict__ Cb,
    const unsigned short* __restrict__ hr, const void* __restrict__ pw, const void* __restrict__ pb,
    const float* __restrict__ gx, float* __restrict__ out,
    const int* __restrict__ flagp) {
    __shared__ __align__(16) short As[128][40];
    __shared__ __align__(16) short Bs[128][40];
    int isf32 = *flagp;
    int tid = threadIdx.x, lane = tid & 63, wave = tid >> 6;
    int wm = (wave >> 1) << 6, wn = (wave & 1) << 6;
    int tileM = blockIdx.x << 7, tileN = blockIdx.y << 7;
    f32x4 z = {0.f, 0.f, 0.f, 0.f};
    f32x4 acc1[4][4], acc2[4][4];
#pragma unroll
    for (int i = 0; i < 4; i++)
#pragma unroll
        for (int j = 0; j < 4; j++) { acc1[i][j] = z; acc2[i][j] = z; }

    for (int kb = 0; kb < 1024; kb += 32) {        // x . Dw^T
        __syncthreads();
        stage_tile(x,  1024, tileM, MROWS - 1, kb, As, tid, isf32);
        stage_tile(Dw, 1024, tileN, 1023, kb, Bs, tid, isf32);
        __syncthreads();
        mfma_tiles(As, Bs, wm, wn, lane, acc1);
    }
    for (int kb = 0; kb < 64; kb += 32) {          // + hs . Cw^T, same acc
        __syncthreads();
        stage_tile(hs, 64, tileM, MROWS - 1, kb, As, tid, 0);
        stage_tile(Cw, 64, tileN, 1023, kb, Bs, tid, isf32);
        __syncthreads();
        mfma_tiles(As, Bs, wm, wn, lane, acc1);
    }
    for (int kb = 0; kb < 128; kb += 32) {         // hr . pw^T
        __syncthreads();
        stage_tile(hr, 128, tileM, MROWS - 1, kb, As, tid, 0);
        stage_tile(pw, 128, tileN, 1023, kb, Bs, tid, isf32);
        __syncthreads();
        mfma_tiles(As, Bs, wm, wn, lane, acc2);
    }
#pragma unroll
    for (int i = 0; i < 4; i++) {
        int r0 = tileM + wm + i * 16 + ((lane >> 4) << 2);
#pragma unroll
        for (int j = 0; j < 4; j++) {
            int col = tileN + wn + j * 16 + (lane & 15);
            float cb  = ldin(Cb, col, isf32) + ldin(Db, col, isf32);
            float pbv = ldin(pb, col, isf32);
#pragma unroll
            for (int r = 0; r < 4; r++) {
                int row = r0 + r;
                float g0 = gx[row * 2], g1 = gx[row * 2 + 1];
                out[(size_t)row * 1024 + col] =
                    g0 * (acc1[i][j][r] + cb) + g1 * (acc2[i][j][r] + pbv);
            }
        }
    }
}

extern "C" void kernel_launch(void* const* d_in, const int* in_sizes, int n_in,
                              void* d_out, int out_size, void* d_ws, size_t ws_size,
                              hipStream_t stream) {
    static const int expect_sizes[16] = {16777216, 4096, 65536, 64, 65536, 1024,
                                         1048576, 1024, 393216, 384, 49152, 384,
                                         131072, 1024, 2048, 2};
    bool order_ok = (n_in == 16);
    if (order_ok)
        for (int i = 0; i < 16; i++)
            if (in_sizes[i] != expect_sizes[i]) { order_ok = false; break; }
    float* out = (float*)d_out;
    if (!order_ok) {
        zero_out_kernel<<<dim3(4096), dim3(256), 0, stream>>>(out);
        return;
    }

    const void* x    = d_in[0];
    const void* Amat = d_in[1];
    const void* Bw   = d_in[2];
    const void* Bb   = d_in[3];
    const void* Cw   = d_in[4];
    const void* Cb   = d_in[5];
    const void* Dw   = d_in[6];
    const void* Db   = d_in[7];
    const void* Wih  = d_in[8];
    const void* bih  = d_in[9];
    const void* Whh  = d_in[10];
    const void* bhh  = d_in[11];
    const void* pw   = d_in[12];
    const void* pb   = d_in[13];
    const void* gw   = d_in[14];
    const void* gb   = d_in[15];

    // d_ws (21.1 MB): flag | gx | hs | hr | bx | ih
    char* ws = (char*)d_ws;
    int*            flg = (int*)(ws);                        //       256 B
    float*          gxw = (float*)(ws + 256);                //   131,072 B
    unsigned short* hsw = (unsigned short*)(ws + 131328);    // 2,097,152 B
    unsigned short* hrw = (unsigned short*)(ws + 2228480);   // 4,194,304 B
    unsigned short* bxw = (unsigned short*)(ws + 6422784);   // 2,097,152 B
    unsigned short* ihw = (unsigned short*)(ws + 8519936);   // 12,582,912 B

    dim3 blk(256);
    sniff_kernel<<<dim3(1), dim3(64), 0, stream>>>((const unsigned short*)x, flg);
    gemm_bt_kernel<<<dim3(128, 3), blk, 0, stream>>>(x, Wih, bih, ihw, MROWS, 384, 1024, flg);
    gemm_bt_kernel<<<dim3(128, 1), blk, 0, stream>>>(x, Bw, Bb, bxw, MROWS, 64, 1024, flg);
    gate_kernel<<<dim3(4096), blk, 0, stream>>>(x, gw, gb, gxw, flg);
    scan_kernel<<<dim3(16), dim3(512), 0, stream>>>(Amat, Whh, bhh, bxw, ihw, hsw, hrw, flg);
    out_kernel<<<dim3(128, 8), blk, 0, stream>>>(x, Dw, Db, hsw, Cw, Cb, hrw, pw, pb, gxw, out, flg);
}

// Round 6
// 1446.734 us; speedup vs baseline: 1.2639x; 1.0528x over previous
//
#include <hip/hip_runtime.h>

// HyMBA block, MI355X — ROUND 13:
// (a) one-time bf16 conversion of x + GEMM weights/biases (ws-gated):
//     gemm/out staging becomes pure bf16x8 copy (half loads, no cvt VALU).
// (b) scan: s_setprio around MFMA cluster (2 waves/SIMD role diversity);
//     chunk staging folded to mid-chunk (tt==8) => no extra chunk barriers.
// R12 carried: 8-wave GRU, broadcast-A flat H, 2-chain MFMA, chunked IH/BX.

#define MROWS 16384   // B*N rows
#define SEQ   2048
#define CH    16      // scan staging chunk (timesteps)
#define NCH   (SEQ / CH)

typedef __attribute__((ext_vector_type(8))) short bf16x8;
typedef __attribute__((ext_vector_type(4))) float f32x4;

__device__ __forceinline__ float bf2f(unsigned short u) {
    union { unsigned int i; float f; } c; c.i = ((unsigned int)u) << 16; return c.f;
}
__device__ __forceinline__ unsigned short f2bf(float f) {
    union { float f; unsigned int i; } c; c.f = f;
    unsigned int x = c.i;
    return (unsigned short)((x + 0x7fffu + ((x >> 16) & 1u)) >> 16);
}
// pack two f32 -> two bf16 (RNE) in one VALU instr
__device__ __forceinline__ unsigned int f2bf_pk(float lo, float hi) {
    unsigned int r;
    asm("v_cvt_pk_bf16_f32 %0, %1, %2" : "=v"(r) : "v"(lo), "v"(hi));
    return r;
}
__device__ __forceinline__ float ldin(const void* p, size_t i, int isf32) {
    return isf32 ? ((const float*)p)[i] : bf2f(((const unsigned short*)p)[i]);
}
__device__ __forceinline__ float sigf(float v) { return 1.f / (1.f + __expf(-v)); }
__device__ __forceinline__ float tanhf_fast(float v) { return 2.f * sigf(2.f * v) - 1.f; }

__global__ void sniff_kernel(const unsigned short* __restrict__ x, int* __restrict__ flag) {
    int tid = threadIdx.x;
    int big = 0;
    for (int i = tid; i < 1024; i += 64) {
        unsigned int e = (x[i] >> 7) & 0xFFu;
        big += (e >= 0xC0u) ? 1 : 0;
    }
#pragma unroll
    for (int off = 32; off; off >>= 1) big += __shfl_down(big, off);
    if (tid == 0) { flag[0] = (big >= 4) ? 1 : 0; flag[1] = 0; }
}

__global__ void zero_out_kernel(float* __restrict__ out) {
    size_t i = ((size_t)blockIdx.x * 256 + threadIdx.x) * 16;
#pragma unroll
    for (int u = 0; u < 16; u++) out[i + u] = 0.f;
}

// ---------------- one-time bf16 conversion ----------------
__device__ __forceinline__ void cvt16(const void* src, unsigned short* dst,
                                      size_t i0, int isf32) {
#pragma unroll
    for (int q = 0; q < 2; q++) {
        size_t i = i0 + q * 8;
        if (isf32) {
            const float* s = (const float*)src + i;
            float4 a = *reinterpret_cast<const float4*>(s);
            float4 b = *reinterpret_cast<const float4*>(s + 4);
            union { bf16x8 v; unsigned int u[4]; } u;
            u.u[0] = f2bf_pk(a.x, a.y); u.u[1] = f2bf_pk(a.z, a.w);
            u.u[2] = f2bf_pk(b.x, b.y); u.u[3] = f2bf_pk(b.z, b.w);
            *reinterpret_cast<bf16x8*>(dst + i) = u.v;
        } else {
            *reinterpret_cast<bf16x8*>(dst + i) =
                *reinterpret_cast<const bf16x8*>((const unsigned short*)src + i);
        }
    }
}

// x: 16,777,216 elems; 4096 blocks x 256 thr x 16 elems
__global__ __launch_bounds__(256) void cvt_x_kernel(
    const void* __restrict__ x, unsigned short* __restrict__ xb,
    const int* __restrict__ flagp) {
    int isf32 = *flagp;
    size_t i0 = ((size_t)blockIdx.x * 256 + threadIdx.x) * 16;
    cvt16(x, xb, i0, isf32);
}

// weights+biases: Dw[0,256) Wih[256,352) pw[352,384) Cw[384,400) Bw[400,416) bias[416]
__global__ __launch_bounds__(256) void cvt_w_kernel(
    const void* __restrict__ Dw,  const void* __restrict__ Wih,
    const void* __restrict__ pw,  const void* __restrict__ Cw,
    const void* __restrict__ Bw,  const void* __restrict__ bih,
    const void* __restrict__ Bb,  const void* __restrict__ Cb,
    const void* __restrict__ Db,  const void* __restrict__ pb,
    unsigned short* __restrict__ Dwb,  unsigned short* __restrict__ Wihb,
    unsigned short* __restrict__ pwb,  unsigned short* __restrict__ Cwb,
    unsigned short* __restrict__ Bwb,  unsigned short* __restrict__ bihb,
    unsigned short* __restrict__ Bbb,  unsigned short* __restrict__ Cbb,
    unsigned short* __restrict__ Dbb,  unsigned short* __restrict__ pbb,
    const int* __restrict__ flagp) {
    int isf32 = *flagp;
    int blk = blockIdx.x, tid = threadIdx.x;
    const void* src; unsigned short* dst; size_t base;
    if (blk < 256)      { src = Dw;  dst = Dwb;  base = (size_t)blk * 4096; }
    else if (blk < 352) { src = Wih; dst = Wihb; base = (size_t)(blk - 256) * 4096; }
    else if (blk < 384) { src = pw;  dst = pwb;  base = (size_t)(blk - 352) * 4096; }
    else if (blk < 400) { src = Cw;  dst = Cwb;  base = (size_t)(blk - 384) * 4096; }
    else if (blk < 416) { src = Bw;  dst = Bwb;  base = (size_t)(blk - 400) * 4096; }
    else {
        for (int i = tid; i < 384; i += 256) bihb[i] = f2bf(ldin(bih, i, isf32));
        if (tid < 64) Bbb[tid] = f2bf(ldin(Bb, tid, isf32));
        for (int i = tid; i < 1024; i += 256) {
            Cbb[i] = f2bf(ldin(Cb, i, isf32));
            Dbb[i] = f2bf(ldin(Db, i, isf32));
            pbb[i] = f2bf(ldin(pb, i, isf32));
        }
        return;
    }
    cvt16(src, dst, base + (size_t)tid * 16, isf32);
}

// ---------------- MFMA GEMM: 128x128 tile, BK=32, 256 threads ----------------
__device__ __forceinline__ void stage_tile(const void* __restrict__ g,
                                           int ld, int row0, int rowmax, int kb,
                                           short (*lds)[40], int tid, int isf32) {
#pragma unroll
    for (int q = 0; q < 2; q++) {
        int oct = q * 256 + tid;
        int row = oct >> 2, c8 = (oct & 3) << 3;
        int gr = row0 + row; if (gr > rowmax) gr = rowmax;
        size_t base = (size_t)gr * ld + kb + c8;
        bf16x8 v;
        if (isf32) {
            const float* gp = (const float*)g + base;
            float4 f0 = *reinterpret_cast<const float4*>(gp);
            float4 f1 = *reinterpret_cast<const float4*>(gp + 4);
            union { bf16x8 v8; unsigned int u[4]; } u;
            u.u[0] = f2bf_pk(f0.x, f0.y);
            u.u[1] = f2bf_pk(f0.z, f0.w);
            u.u[2] = f2bf_pk(f1.x, f1.y);
            u.u[3] = f2bf_pk(f1.z, f1.w);
            v = u.v8;
        } else {
            v = *reinterpret_cast<const bf16x8*>((const unsigned short*)g + base);
        }
        *reinterpret_cast<bf16x8*>(&lds[row][c8]) = v;
    }
}

// A-frag: m=lane&15, k=(lane>>4)*8+j ; B-frag: n=lane&15 (W stored [n][k]).
// C/D: col=lane&15, row=(lane>>4)*4+reg   [m89-verified]
__device__ __forceinline__ void mfma_tiles(const short (*As)[40], const short (*Bs)[40],
                                           int wm, int wn, int lane, f32x4 (*acc)[4]) {
    bf16x8 af[4], bfr[4];
    int m = lane & 15, ko = (lane >> 4) << 3;
#pragma unroll
    for (int i = 0; i < 4; i++)
        af[i] = *reinterpret_cast<const bf16x8*>(&As[wm + i * 16 + m][ko]);
#pragma unroll
    for (int j = 0; j < 4; j++)
        bfr[j] = *reinterpret_cast<const bf16x8*>(&Bs[wn + j * 16 + m][ko]);
#pragma unroll
    for (int i = 0; i < 4; i++)
#pragma unroll
        for (int j = 0; j < 4; j++)
            acc[i][j] = __builtin_amdgcn_mfma_f32_16x16x32_bf16(af[i], bfr[j], acc[i][j], 0, 0, 0);
}

// C[M,N] = A[M,K]*W[N,K]^T + bias[N]; bf16 staging out
__global__ __launch_bounds__(256) void gemm_bt_kernel(
    const void* __restrict__ A, const void* __restrict__ W,
    const void* __restrict__ bias, unsigned short* __restrict__ C,
    int M, int N, int K, const int* __restrict__ flagp) {
    __shared__ __align__(16) short As[128][40];
    __shared__ __align__(16) short Bs[128][40];
    int isf32 = *flagp;
    int tid = threadIdx.x, lane = tid & 63, wave = tid >> 6;
    int wm = (wave >> 1) << 6, wn = (wave & 1) << 6;
    int tileM = blockIdx.x << 7, tileN = blockIdx.y << 7;
    f32x4 acc[4][4];
    f32x4 z = {0.f, 0.f, 0.f, 0.f};
#pragma unroll
    for (int i = 0; i < 4; i++)
#pragma unroll
        for (int j = 0; j < 4; j++) acc[i][j] = z;

    for (int kb = 0; kb < K; kb += 32) {
        __syncthreads();
        stage_tile(A, K, tileM, M - 1, kb, As, tid, isf32);
        stage_tile(W, K, tileN, N - 1, kb, Bs, tid, isf32);
        __syncthreads();
        mfma_tiles(As, Bs, wm, wn, lane, acc);
    }
#pragma unroll
    for (int i = 0; i < 4; i++) {
#pragma unroll
        for (int j = 0; j < 4; j++) {
            int col = tileN + wn + j * 16 + (lane & 15);
            if (col < N) {
                float bv = ldin(bias, col, isf32);
                int row0 = tileM + wm + i * 16 + ((lane >> 4) << 2);
                unsigned int pk0 = f2bf_pk(acc[i][j][0] + bv, acc[i][j][1] + bv);
                unsigned int pk1 = f2bf_pk(acc[i][j][2] + bv, acc[i][j][3] + bv);
                C[(size_t)(row0 + 0) * N + col] = (unsigned short)(pk0 & 0xFFFFu);
                C[(size_t)(row0 + 1) * N + col] = (unsigned short)(pk0 >> 16);
                C[(size_t)(row0 + 2) * N + col] = (unsigned short)(pk1 & 0xFFFFu);
                C[(size_t)(row0 + 3) * N + col] = (unsigned short)(pk1 >> 16);
            }
        }
    }
}

// gx[row][2] = sigmoid(x_row . gate_w[g] + gate_b[g])
__global__ __launch_bounds__(256) void gate_kernel(
    const void* __restrict__ x, const void* __restrict__ gw,
    const void* __restrict__ gb, float* __restrict__ gx, const int* __restrict__ flagp) {
    int isf32 = *flagp;
    int row = (blockIdx.x << 2) + (threadIdx.x >> 6);
    int lane = threadIdx.x & 63;
    size_t xoff = (size_t)row * 1024 + lane * 16;
    float a0 = 0.f, a1 = 0.f;
#pragma unroll
    for (int q = 0; q < 2; q++) {
#pragma unroll
        for (int e = 0; e < 8; e++) {
            size_t k = q * 8 + e;
            float xf = ldin(x, xoff + k, isf32);
            a0 += xf * ldin(gw, (size_t)lane * 16 + k, isf32);
            a1 += xf * ldin(gw, 1024 + (size_t)lane * 16 + k, isf32);
        }
    }
#pragma unroll
    for (int off = 32; off > 0; off >>= 1) {
        a0 += __shfl_down(a0, off);
        a1 += __shfl_down(a1, off);
    }
    if (lane == 0) {
        gx[row * 2]     = sigf(a0 + ldin(gb, 0, isf32));
        gx[row * 2 + 1] = sigf(a1 + ldin(gb, 1, isf32));
    }
}

// ---------------- MFMA sequential scans ----------------
// blocks 0..7: GRU (batch b). 512 thr = 8 waves (2/SIMD); wave w owns the
// r/z/n tile triple for cols [16w, 16w+16). setprio(1) around MFMA cluster.
// IH chunk staging folded to mid-chunk (tt==8): no chunk-boundary barrier.
// blocks 8..15: SSM, wave 0 only.
__global__ __launch_bounds__(512) void scan_kernel(
    const void* __restrict__ Amat,            // [64][64]
    const void* __restrict__ Whh,             // [384][128]
    const void* __restrict__ bhh,             // [384]
    const unsigned short* __restrict__ bxw,   // [MROWS][64]  bf16 (Bb included)
    const unsigned short* __restrict__ ihw,   // [MROWS][384] bf16 (b_ih included)
    unsigned short* __restrict__ hsw,         // [MROWS][64]
    unsigned short* __restrict__ hrw,         // [MROWS][128]
    const int* __restrict__ flagp) {
    int isf32 = *flagp;
    int b = blockIdx.x & 7;
    size_t rowbase = (size_t)b * SEQ;
    f32x4 zf = {0.f, 0.f, 0.f, 0.f};

    if (blockIdx.x < 8) {
        // ---------------- GRU (8 waves) ----------------
        __shared__ __align__(16) unsigned short H[2][128];       // flat h, dbuf
        __shared__ __align__(16) unsigned short IH[2][CH][384];  // ih chunk, dbuf (24.6KB)
        int tid = threadIdx.x, lane = tid & 63, w = tid >> 6;    // w in 0..7
        int col = lane & 15, quad = lane >> 4;
        int o = w * 16 + col;                                    // this wave's col
        if (tid < 256) ((unsigned short*)H)[tid] = 0;
        // static B-fragments: g=0(r),1(z),2(n): Whh row g*128+o, k = c*32+quad*8+e
        bf16x8 Bf[3][4];
#pragma unroll
        for (int g = 0; g < 3; g++) {
            int n = g * 128 + o;
#pragma unroll
            for (int c = 0; c < 4; c++) {
                int k0 = c * 32 + quad * 8;
                bf16x8 v;
#pragma unroll
                for (int e = 0; e < 8; e++)
                    v[e] = (short)f2bf(ldin(Whh, (size_t)n * 128 + k0 + e, isf32));
                Bf[g][c] = v;
            }
        }
        float bias_r = ldin(bhh, o, isf32);
        float bias_z = ldin(bhh, 128 + o, isf32);
        float bias_n = ldin(bhh, 256 + o, isf32);
        float hprev = 0.f;
        bool gl = (quad == 0);
        // chunk prologue: chunk0 -> IH[0]; issue chunk1 loads (768 bf16x8/chunk)
        const unsigned short* ihbase = ihw + rowbase * 384;
        bf16x8 stg0, stg1;
        stg0 = *reinterpret_cast<const bf16x8*>(ihbase + (size_t)tid * 8);
        if (tid < 256) stg1 = *reinterpret_cast<const bf16x8*>(ihbase + (size_t)(512 + tid) * 8);
        *reinterpret_cast<bf16x8*>(&IH[0][0][0] + (size_t)tid * 8) = stg0;
        if (tid < 256) *reinterpret_cast<bf16x8*>(&IH[0][0][0] + (size_t)(512 + tid) * 8) = stg1;
        stg0 = *reinterpret_cast<const bf16x8*>(ihbase + (size_t)CH * 384 + (size_t)tid * 8);
        if (tid < 256) stg1 = *reinterpret_cast<const bf16x8*>(ihbase + (size_t)CH * 384 + (size_t)(512 + tid) * 8);
        __syncthreads();

        int p = 0;
        for (int c = 0; c < NCH; c++) {
            int cur = c & 1;
            for (int tt = 0; tt < CH; tt++) {
                int t = c * CH + tt;
                // broadcast A-frags: uniform per quad (4 addrs/wave)
                bf16x8 Af[4];
#pragma unroll
                for (int cc = 0; cc < 4; cc++)
                    Af[cc] = *reinterpret_cast<const bf16x8*>(&H[p][cc * 32 + quad * 8]);
                float ir  = bf2f(IH[cur][tt][o]);
                float iz  = bf2f(IH[cur][tt][128 + o]);
                float inn = bf2f(IH[cur][tt][256 + o]);
                // 3 gates x two parallel 2-chains (K halves)
                f32x4 accL[3], accH[3];
#pragma unroll
                for (int g = 0; g < 3; g++) { accL[g] = zf; accH[g] = zf; }
                __builtin_amdgcn_s_setprio(1);
#pragma unroll
                for (int g = 0; g < 3; g++) {
                    accL[g] = __builtin_amdgcn_mfma_f32_16x16x32_bf16(Af[0], Bf[g][0], accL[g], 0, 0, 0);
                    accH[g] = __builtin_amdgcn_mfma_f32_16x16x32_bf16(Af[2], Bf[g][2], accH[g], 0, 0, 0);
                    accL[g] = __builtin_amdgcn_mfma_f32_16x16x32_bf16(Af[1], Bf[g][1], accL[g], 0, 0, 0);
                    accH[g] = __builtin_amdgcn_mfma_f32_16x16x32_bf16(Af[3], Bf[g][3], accH[g], 0, 0, 0);
                }
                __builtin_amdgcn_s_setprio(0);
                // mid-chunk staging: write chunk c+1 (loaded ~CH steps ago),
                // issue chunk c+2 loads — overlaps epilogue/barrier, no extra barrier
                if (tt == 8) {
                    if (c + 1 < NCH) {
                        unsigned short* dst = &IH[(c + 1) & 1][0][0];
                        *reinterpret_cast<bf16x8*>(dst + (size_t)tid * 8) = stg0;
                        if (tid < 256) *reinterpret_cast<bf16x8*>(dst + (size_t)(512 + tid) * 8) = stg1;
                    }
                    if (c + 2 < NCH) {
                        const unsigned short* src = ihbase + (size_t)(c + 2) * CH * 384;
                        stg0 = *reinterpret_cast<const bf16x8*>(src + (size_t)tid * 8);
                        if (tid < 256) stg1 = *reinterpret_cast<const bf16x8*>(src + (size_t)(512 + tid) * 8);
                    }
                }
                float sr = accL[0][0] + accH[0][0];
                float sz = accL[1][0] + accH[1][0];
                float sn = accL[2][0] + accH[2][0];
                float r  = sigf(ir + sr + bias_r);
                float zg = sigf(iz + sz + bias_z);
                float n  = tanhf_fast(inn + r * (sn + bias_n));
                float hnew = (1.f - zg) * n + zg * hprev;
                hprev = hnew;
                if (gl) {
                    unsigned short hb = f2bf(hnew);
                    H[p ^ 1][o] = hb;
                    hrw[(rowbase + t) * 128 + o] = hb;
                }
                asm volatile("s_waitcnt lgkmcnt(0)" ::: "memory");
                __builtin_amdgcn_s_barrier();
                asm volatile("" ::: "memory");
                p ^= 1;
            }
        }
    } else {
        // ---------------- SSM (wave 0 only) ----------------
        if (threadIdx.x >= 64) return;
        int lane = threadIdx.x, col = lane & 15, quad = lane >> 4;
        __shared__ __align__(16) unsigned short Hs[2][64];       // flat h, dbuf
        __shared__ __align__(16) unsigned short BX[2][CH][64];   // bx chunk, dbuf (4KB)
        ((unsigned short*)Hs)[lane] = 0;
        ((unsigned short*)Hs)[64 + lane] = 0;
        bf16x8 Bf[4][2];
#pragma unroll
        for (int l = 0; l < 4; l++) {
            int n = l * 16 + col;
#pragma unroll
            for (int c = 0; c < 2; c++) {
                int k0 = c * 32 + quad * 8;
                bf16x8 v;
#pragma unroll
                for (int e = 0; e < 8; e++)
                    v[e] = (short)f2bf(ldin(Amat, (size_t)n * 64 + k0 + e, isf32));
                Bf[l][c] = v;
            }
        }
        bool gl = (quad == 0);
        const unsigned short* bxbase = bxw + rowbase * 64;
        bf16x8 stg[2];
#pragma unroll
        for (int q = 0; q < 2; q++)
            stg[q] = *reinterpret_cast<const bf16x8*>(bxbase + (size_t)(q * 64 + lane) * 8);
#pragma unroll
        for (int q = 0; q < 2; q++)
            *reinterpret_cast<bf16x8*>(&BX[0][0][0] + (size_t)(q * 64 + lane) * 8) = stg[q];
#pragma unroll
        for (int q = 0; q < 2; q++)
            stg[q] = *reinterpret_cast<const bf16x8*>(bxbase + (size_t)CH * 64 + (size_t)(q * 64 + lane) * 8);
        asm volatile("s_waitcnt lgkmcnt(0)" ::: "memory");

        int p = 0;
        for (int c = 0; c < NCH; c++) {
            int cur = c & 1;
            for (int tt = 0; tt < CH; tt++) {
                int t = c * CH + tt;
                bf16x8 Af[2];
#pragma unroll
                for (int cc = 0; cc < 2; cc++)
                    Af[cc] = *reinterpret_cast<const bf16x8*>(&Hs[p][cc * 32 + quad * 8]);
                float bx[4];
#pragma unroll
                for (int l = 0; l < 4; l++) bx[l] = bf2f(BX[cur][tt][l * 16 + col]);
                f32x4 acc[4];
#pragma unroll
                for (int l = 0; l < 4; l++) acc[l] = zf;
#pragma unroll
                for (int l = 0; l < 4; l++)
#pragma unroll
                    for (int cc = 0; cc < 2; cc++)
                        acc[l] = __builtin_amdgcn_mfma_f32_16x16x32_bf16(Af[cc], Bf[l][cc], acc[l], 0, 0, 0);
                if (tt == 8) {
                    if (c + 1 < NCH) {
                        unsigned short* dst = &BX[(c + 1) & 1][0][0];
#pragma unroll
                        for (int q = 0; q < 2; q++)
                            *reinterpret_cast<bf16x8*>(dst + (size_t)(q * 64 + lane) * 8) = stg[q];
                    }
                    if (c + 2 < NCH) {
#pragma unroll
                        for (int q = 0; q < 2; q++)
                            stg[q] = *reinterpret_cast<const bf16x8*>(
                                bxbase + (size_t)(c + 2) * CH * 64 + (size_t)(q * 64 + lane) * 8);
                    }
                }
#pragma unroll
                for (int l = 0; l < 4; l++) {
                    int o = l * 16 + col;
                    float v = acc[l][0] + bx[l];
                    float hv = v * sigf(v);
                    unsigned short hb = f2bf(hv);
                    if (gl) {
                        Hs[p ^ 1][o] = hb;
                        hsw[(rowbase + t) * 64 + o] = hb;
                    }
                }
                asm volatile("s_waitcnt lgkmcnt(0)" ::: "memory");
                p ^= 1;
            }
        }
    }
}

// out[row,col] = g0*(x.Dw^T + hs.Cw^T + Cb + Db) + g1*(hr.pw^T + pb) — f32 store
__global__ __launch_bounds__(256) void out_kernel(
    const void* __restrict__ x,  const void* __restrict__ Dw, const void* __restrict__ Db,
    const unsigned short* __restrict__ hs, const void* __restrict__ Cw, const void* __restrict__ Cb,
    const unsigned short* __restrict__ hr, const void* __restrict__ pw, const void* __restrict__ pb,
    const float* __restrict__ gx, float* __restrict__ out,
    const int* __restrict__ flagp) {
    __shared__ __align__(16) short As[128][40];
    __shared__ __align__(16) short Bs[128][40];
    int isf32 = *flagp;
    int tid = threadIdx.x, lane = tid & 63, wave = tid >> 6;
    int wm = (wave >> 1) << 6, wn = (wave & 1) << 6;
    int tileM = blockIdx.x << 7, tileN = blockIdx.y << 7;
    f32x4 z = {0.f, 0.f, 0.f, 0.f};
    f32x4 acc1[4][4], acc2[4][4];
#pragma unroll
    for (int i = 0; i < 4; i++)
#pragma unroll
        for (int j = 0; j < 4; j++) { acc1[i][j] = z; acc2[i][j] = z; }

    for (int kb = 0; kb < 1024; kb += 32) {        // x . Dw^T
        __syncthreads();
        stage_tile(x,  1024, tileM, MROWS - 1, kb, As, tid, isf32);
        stage_tile(Dw, 1024, tileN, 1023, kb, Bs, tid, isf32);
        __syncthreads();
        mfma_tiles(As, Bs, wm, wn, lane, acc1);
    }
    for (int kb = 0; kb < 64; kb += 32) {          // + hs . Cw^T, same acc
        __syncthreads();
        stage_tile(hs, 64, tileM, MROWS - 1, kb, As, tid, 0);
        stage_tile(Cw, 64, tileN, 1023, kb, Bs, tid, isf32);
        __syncthreads();
        mfma_tiles(As, Bs, wm, wn, lane, acc1);
    }
    for (int kb = 0; kb < 128; kb += 32) {         // hr . pw^T
        __syncthreads();
        stage_tile(hr, 128, tileM, MROWS - 1, kb, As, tid, 0);
        stage_tile(pw, 128, tileN, 1023, kb, Bs, tid, isf32);
        __syncthreads();
        mfma_tiles(As, Bs, wm, wn, lane, acc2);
    }
#pragma unroll
    for (int i = 0; i < 4; i++) {
        int r0 = tileM + wm + i * 16 + ((lane >> 4) << 2);
#pragma unroll
        for (int j = 0; j < 4; j++) {
            int col = tileN + wn + j * 16 + (lane & 15);
            float cb  = ldin(Cb, col, isf32) + ldin(Db, col, isf32);
            float pbv = ldin(pb, col, isf32);
#pragma unroll
            for (int r = 0; r < 4; r++) {
                int row = r0 + r;
                float g0 = gx[row * 2], g1 = gx[row * 2 + 1];
                out[(size_t)row * 1024 + col] =
                    g0 * (acc1[i][j][r] + cb) + g1 * (acc2[i][j][r] + pbv);
            }
        }
    }
}

extern "C" void kernel_launch(void* const* d_in, const int* in_sizes, int n_in,
                              void* d_out, int out_size, void* d_ws, size_t ws_size,
                              hipStream_t stream) {
    static const int expect_sizes[16] = {16777216, 4096, 65536, 64, 65536, 1024,
                                         1048576, 1024, 393216, 384, 49152, 384,
                                         131072, 1024, 2048, 2};
    bool order_ok = (n_in == 16);
    if (order_ok)
        for (int i = 0; i < 16; i++)
            if (in_sizes[i] != expect_sizes[i]) { order_ok = false; break; }
    float* out = (float*)d_out;
    if (!order_ok) {
        zero_out_kernel<<<dim3(4096), dim3(256), 0, stream>>>(out);
        return;
    }

    const void* x    = d_in[0];
    const void* Amat = d_in[1];
    const void* Bw   = d_in[2];
    const void* Bb   = d_in[3];
    const void* Cw   = d_in[4];
    const void* Cb   = d_in[5];
    const void* Dw   = d_in[6];
    const void* Db   = d_in[7];
    const void* Wih  = d_in[8];
    const void* bih  = d_in[9];
    const void* Whh  = d_in[10];
    const void* bhh  = d_in[11];
    const void* pw   = d_in[12];
    const void* pb   = d_in[13];
    const void* gw   = d_in[14];
    const void* gb   = d_in[15];

    // d_ws base (21.1 MB): flag | gx | hs | hr | bx | ih ; then optional bf16 mirrors
    char* ws = (char*)d_ws;
    int*            flg = (int*)(ws);                        //       256 B (flg[0]=sniff, flg[1]=0)
    float*          gxw = (float*)(ws + 256);                //   131,072 B
    unsigned short* hsw = (unsigned short*)(ws + 131328);    // 2,097,152 B
    unsigned short* hrw = (unsigned short*)(ws + 2228480);   // 4,194,304 B
    unsigned short* bxw = (unsigned short*)(ws + 6422784);   // 2,097,152 B
    unsigned short* ihw = (unsigned short*)(ws + 8519936);   // 12,582,912 B
    // bf16 mirrors (ws-gated)
    unsigned short* xb   = (unsigned short*)(ws + 21102848); // 33,554,432 B
    unsigned short* Dwb  = (unsigned short*)(ws + 54657280); //  2,097,152 B
    unsigned short* Wihb = (unsigned short*)(ws + 56754432); //    786,432 B
    unsigned short* pwb  = (unsigned short*)(ws + 57540864); //    262,144 B
    unsigned short* Cwb  = (unsigned short*)(ws + 57803008); //    131,072 B
    unsigned short* Bwb  = (unsigned short*)(ws + 57934080); //    131,072 B
    unsigned short* bihb = (unsigned short*)(ws + 58065152); //        768 B (4KB slot)
    unsigned short* Bbb  = (unsigned short*)(ws + 58069248);
    unsigned short* Cbb  = (unsigned short*)(ws + 58073344);
    unsigned short* Dbb  = (unsigned short*)(ws + 58077440);
    unsigned short* pbb  = (unsigned short*)(ws + 58081536);
    bool big = ws_size >= 58085632ull;

    dim3 blk(256);
    sniff_kernel<<<dim3(1), dim3(64), 0, stream>>>((const unsigned short*)x, flg);
    if (big) {
        cvt_x_kernel<<<dim3(4096), blk, 0, stream>>>(x, xb, flg);
        cvt_w_kernel<<<dim3(417), blk, 0, stream>>>(
            Dw, Wih, pw, Cw, Bw, bih, Bb, Cb, Db, pb,
            Dwb, Wihb, pwb, Cwb, Bwb, bihb, Bbb, Cbb, Dbb, pbb, flg);
        gemm_bt_kernel<<<dim3(128, 3), blk, 0, stream>>>(xb, Wihb, bihb, ihw, MROWS, 384, 1024, flg + 1);
        gemm_bt_kernel<<<dim3(128, 1), blk, 0, stream>>>(xb, Bwb, Bbb, bxw, MROWS, 64, 1024, flg + 1);
        gate_kernel<<<dim3(4096), blk, 0, stream>>>(x, gw, gb, gxw, flg);
        scan_kernel<<<dim3(16), dim3(512), 0, stream>>>(Amat, Whh, bhh, bxw, ihw, hsw, hrw, flg);
        out_kernel<<<dim3(128, 8), blk, 0, stream>>>(xb, Dwb, Dbb, hsw, Cwb, Cbb, hrw, pwb, pbb, gxw, out, flg + 1);
    } else {
        gemm_bt_kernel<<<dim3(128, 3), blk, 0, stream>>>(x, Wih, bih, ihw, MROWS, 384, 1024, flg);
        gemm_bt_kernel<<<dim3(128, 1), blk, 0, stream>>>(x, Bw, Bb, bxw, MROWS, 64, 1024, flg);
        gate_kernel<<<dim3(4096), blk, 0, stream>>>(x, gw, gb, gxw, flg);
        scan_kernel<<<dim3(16), dim3(512), 0, stream>>>(Amat, Whh, bhh, bxw, ihw, hsw, hrw, flg);
        out_kernel<<<dim3(128, 8), blk, 0, stream>>>(x, Dw, Db, hsw, Cw, Cb, hrw, pw, pb, gxw, out, flg);
    }
}

// Round 7
// 1303.389 us; speedup vs baseline: 1.4029x; 1.1100x over previous
//
#include <hip/hip_runtime.h>

// HyMBA block, MI355X — ROUND 14: launch fusion + scan micro-cuts.
// (1) gate folded into scan_kernel as blocks 16..2063 (runs on idle CUs,
//     hidden under the 1ms scan). (2) ih+bx GEMMs fused into one grid(128,4)
//     launch. (3) cvt_x+cvt_w fused. 9 -> 5 launches.
// (4) scan: zf passed as C to first MFMA of each chain (no acc zero-init),
//     setprio dropped (null), chunk staging hoisted out of the step loop.
// Per-SIMD MFMA floor (corrected): 24 MFMA/SIMD/step x 16.1 cy = ~387 cy.

#define MROWS 16384   // B*N rows
#define SEQ   2048
#define CH    16      // scan staging chunk (timesteps)
#define NCH   (SEQ / CH)

typedef __attribute__((ext_vector_type(8))) short bf16x8;
typedef __attribute__((ext_vector_type(4))) float f32x4;

__device__ __forceinline__ float bf2f(unsigned short u) {
    union { unsigned int i; float f; } c; c.i = ((unsigned int)u) << 16; return c.f;
}
__device__ __forceinline__ unsigned short f2bf(float f) {
    union { float f; unsigned int i; } c; c.f = f;
    unsigned int x = c.i;
    return (unsigned short)((x + 0x7fffu + ((x >> 16) & 1u)) >> 16);
}
// pack two f32 -> two bf16 (RNE) in one VALU instr
__device__ __forceinline__ unsigned int f2bf_pk(float lo, float hi) {
    unsigned int r;
    asm("v_cvt_pk_bf16_f32 %0, %1, %2" : "=v"(r) : "v"(lo), "v"(hi));
    return r;
}
__device__ __forceinline__ float ldin(const void* p, size_t i, int isf32) {
    return isf32 ? ((const float*)p)[i] : bf2f(((const unsigned short*)p)[i]);
}
__device__ __forceinline__ float sigf(float v) { return 1.f / (1.f + __expf(-v)); }
__device__ __forceinline__ float tanhf_fast(float v) { return 2.f * sigf(2.f * v) - 1.f; }

__global__ void sniff_kernel(const unsigned short* __restrict__ x, int* __restrict__ flag) {
    int tid = threadIdx.x;
    int big = 0;
    for (int i = tid; i < 1024; i += 64) {
        unsigned int e = (x[i] >> 7) & 0xFFu;
        big += (e >= 0xC0u) ? 1 : 0;
    }
#pragma unroll
    for (int off = 32; off; off >>= 1) big += __shfl_down(big, off);
    if (tid == 0) { flag[0] = (big >= 4) ? 1 : 0; flag[1] = 0; }
}

__global__ void zero_out_kernel(float* __restrict__ out) {
    size_t i = ((size_t)blockIdx.x * 256 + threadIdx.x) * 16;
#pragma unroll
    for (int u = 0; u < 16; u++) out[i + u] = 0.f;
}

// ---------------- one-time bf16 conversion (x + weights, fused) ----------------
__device__ __forceinline__ void cvt16(const void* src, unsigned short* dst,
                                      size_t i0, int isf32) {
#pragma unroll
    for (int q = 0; q < 2; q++) {
        size_t i = i0 + q * 8;
        if (isf32) {
            const float* s = (const float*)src + i;
            float4 a = *reinterpret_cast<const float4*>(s);
            float4 b = *reinterpret_cast<const float4*>(s + 4);
            union { bf16x8 v; unsigned int u[4]; } u;
            u.u[0] = f2bf_pk(a.x, a.y); u.u[1] = f2bf_pk(a.z, a.w);
            u.u[2] = f2bf_pk(b.x, b.y); u.u[3] = f2bf_pk(b.z, b.w);
            *reinterpret_cast<bf16x8*>(dst + i) = u.v;
        } else {
            *reinterpret_cast<bf16x8*>(dst + i) =
                *reinterpret_cast<const bf16x8*>((const unsigned short*)src + i);
        }
    }
}

// blocks 0..4095: x (16 elems/thr). blocks 4096..4512: weights/biases.
__global__ __launch_bounds__(256) void cvt_all_kernel(
    const void* __restrict__ x,
    const void* __restrict__ Dw,  const void* __restrict__ Wih,
    const void* __restrict__ pw,  const void* __restrict__ Cw,
    const void* __restrict__ Bw,  const void* __restrict__ bih,
    const void* __restrict__ Bb,  const void* __restrict__ Cb,
    const void* __restrict__ Db,  const void* __restrict__ pb,
    unsigned short* __restrict__ xb,
    unsigned short* __restrict__ Dwb,  unsigned short* __restrict__ Wihb,
    unsigned short* __restrict__ pwb,  unsigned short* __restrict__ Cwb,
    unsigned short* __restrict__ Bwb,  unsigned short* __restrict__ bihb,
    unsigned short* __restrict__ Bbb,  unsigned short* __restrict__ Cbb,
    unsigned short* __restrict__ Dbb,  unsigned short* __restrict__ pbb,
    const int* __restrict__ flagp) {
    int isf32 = *flagp;
    int tid = threadIdx.x;
    if (blockIdx.x < 4096) {
        size_t i0 = ((size_t)blockIdx.x * 256 + tid) * 16;
        cvt16(x, xb, i0, isf32);
        return;
    }
    int blk = blockIdx.x - 4096;
    const void* src; unsigned short* dst; size_t base;
    if (blk < 256)      { src = Dw;  dst = Dwb;  base = (size_t)blk * 4096; }
    else if (blk < 352) { src = Wih; dst = Wihb; base = (size_t)(blk - 256) * 4096; }
    else if (blk < 384) { src = pw;  dst = pwb;  base = (size_t)(blk - 352) * 4096; }
    else if (blk < 400) { src = Cw;  dst = Cwb;  base = (size_t)(blk - 384) * 4096; }
    else if (blk < 416) { src = Bw;  dst = Bwb;  base = (size_t)(blk - 400) * 4096; }
    else {
        for (int i = tid; i < 384; i += 256) bihb[i] = f2bf(ldin(bih, i, isf32));
        if (tid < 64) Bbb[tid] = f2bf(ldin(Bb, tid, isf32));
        for (int i = tid; i < 1024; i += 256) {
            Cbb[i] = f2bf(ldin(Cb, i, isf32));
            Dbb[i] = f2bf(ldin(Db, i, isf32));
            pbb[i] = f2bf(ldin(pb, i, isf32));
        }
        return;
    }
    cvt16(src, dst, base + (size_t)tid * 16, isf32);
}

// ---------------- MFMA GEMM: 128x128 tile, BK=32, 256 threads ----------------
__device__ __forceinline__ void stage_tile(const void* __restrict__ g,
                                           int ld, int row0, int rowmax, int kb,
                                           short (*lds)[40], int tid, int isf32) {
#pragma unroll
    for (int q = 0; q < 2; q++) {
        int oct = q * 256 + tid;
        int row = oct >> 2, c8 = (oct & 3) << 3;
        int gr = row0 + row; if (gr > rowmax) gr = rowmax;
        size_t base = (size_t)gr * ld + kb + c8;
        bf16x8 v;
        if (isf32) {
            const float* gp = (const float*)g + base;
            float4 f0 = *reinterpret_cast<const float4*>(gp);
            float4 f1 = *reinterpret_cast<const float4*>(gp + 4);
            union { bf16x8 v8; unsigned int u[4]; } u;
            u.u[0] = f2bf_pk(f0.x, f0.y);
            u.u[1] = f2bf_pk(f0.z, f0.w);
            u.u[2] = f2bf_pk(f1.x, f1.y);
            u.u[3] = f2bf_pk(f1.z, f1.w);
            v = u.v8;
        } else {
            v = *reinterpret_cast<const bf16x8*>((const unsigned short*)g + base);
        }
        *reinterpret_cast<bf16x8*>(&lds[row][c8]) = v;
    }
}

// A-frag: m=lane&15, k=(lane>>4)*8+j ; B-frag: n=lane&15 (W stored [n][k]).
// C/D: col=lane&15, row=(lane>>4)*4+reg   [m89-verified]
__device__ __forceinline__ void mfma_tiles(const short (*As)[40], const short (*Bs)[40],
                                           int wm, int wn, int lane, f32x4 (*acc)[4]) {
    bf16x8 af[4], bfr[4];
    int m = lane & 15, ko = (lane >> 4) << 3;
#pragma unroll
    for (int i = 0; i < 4; i++)
        af[i] = *reinterpret_cast<const bf16x8*>(&As[wm + i * 16 + m][ko]);
#pragma unroll
    for (int j = 0; j < 4; j++)
        bfr[j] = *reinterpret_cast<const bf16x8*>(&Bs[wn + j * 16 + m][ko]);
#pragma unroll
    for (int i = 0; i < 4; i++)
#pragma unroll
        for (int j = 0; j < 4; j++)
            acc[i][j] = __builtin_amdgcn_mfma_f32_16x16x32_bf16(af[i], bfr[j], acc[i][j], 0, 0, 0);
}

// fused ih+bx GEMM: y<3 -> C1=A.Wih^T (N=384), y==3 -> C2=A.Bw^T (N=64). K=1024.
__global__ __launch_bounds__(256) void gemm_fused_kernel(
    const void* __restrict__ A,
    const void* __restrict__ Wih, const void* __restrict__ bih, unsigned short* __restrict__ C1,
    const void* __restrict__ Bw,  const void* __restrict__ Bb,  unsigned short* __restrict__ C2,
    const int* __restrict__ flagp) {
    __shared__ __align__(16) short As[128][40];
    __shared__ __align__(16) short Bs[128][40];
    int isf32 = *flagp;
    int tid = threadIdx.x, lane = tid & 63, wave = tid >> 6;
    int wm = (wave >> 1) << 6, wn = (wave & 1) << 6;
    int tileM = blockIdx.x << 7;
    const void* W; const void* bias; unsigned short* C; int N, tileN;
    if (blockIdx.y < 3) { W = Wih; bias = bih; C = C1; N = 384; tileN = blockIdx.y << 7; }
    else                { W = Bw;  bias = Bb;  C = C2; N = 64;  tileN = 0; }
    f32x4 acc[4][4];
    f32x4 z = {0.f, 0.f, 0.f, 0.f};
#pragma unroll
    for (int i = 0; i < 4; i++)
#pragma unroll
        for (int j = 0; j < 4; j++) acc[i][j] = z;

    for (int kb = 0; kb < 1024; kb += 32) {
        __syncthreads();
        stage_tile(A, 1024, tileM, MROWS - 1, kb, As, tid, isf32);
        stage_tile(W, 1024, tileN, N - 1, kb, Bs, tid, isf32);
        __syncthreads();
        mfma_tiles(As, Bs, wm, wn, lane, acc);
    }
#pragma unroll
    for (int i = 0; i < 4; i++) {
#pragma unroll
        for (int j = 0; j < 4; j++) {
            int col = tileN + wn + j * 16 + (lane & 15);
            if (col < N) {
                float bv = ldin(bias, col, isf32);
                int row0 = tileM + wm + i * 16 + ((lane >> 4) << 2);
                unsigned int pk0 = f2bf_pk(acc[i][j][0] + bv, acc[i][j][1] + bv);
                unsigned int pk1 = f2bf_pk(acc[i][j][2] + bv, acc[i][j][3] + bv);
                C[(size_t)(row0 + 0) * N + col] = (unsigned short)(pk0 & 0xFFFFu);
                C[(size_t)(row0 + 1) * N + col] = (unsigned short)(pk0 >> 16);
                C[(size_t)(row0 + 2) * N + col] = (unsigned short)(pk1 & 0xFFFFu);
                C[(size_t)(row0 + 3) * N + col] = (unsigned short)(pk1 >> 16);
            }
        }
    }
}

// ---------------- MFMA sequential scans + hidden gate ----------------
// blocks 0..7: GRU (batch b), 512 thr = 8 waves; wave w owns r/z/n for cols
// [16w,16w+16). blocks 8..15: SSM, wave 0 only. blocks 16..2063: gate
// (8 rows/block) — independent of scan, runs on idle CUs, feeds out_kernel.
__global__ __launch_bounds__(512) void scan_kernel(
    const void* __restrict__ Amat,            // [64][64]
    const void* __restrict__ Whh,             // [384][128]
    const void* __restrict__ bhh,             // [384]
    const unsigned short* __restrict__ bxw,   // [MROWS][64]  bf16 (Bb included)
    const unsigned short* __restrict__ ihw,   // [MROWS][384] bf16 (b_ih included)
    unsigned short* __restrict__ hsw,         // [MROWS][64]
    unsigned short* __restrict__ hrw,         // [MROWS][128]
    const void* __restrict__ x,  const void* __restrict__ gw,
    const void* __restrict__ gb, float* __restrict__ gx,
    const int* __restrict__ flagp) {
    int isf32 = *flagp;
    f32x4 zf = {0.f, 0.f, 0.f, 0.f};

    if (blockIdx.x >= 16) {
        // ---------------- gate (hidden under scan) ----------------
        int row = (int)(blockIdx.x - 16) * 8 + (threadIdx.x >> 6);
        int lane = threadIdx.x & 63;
        size_t xoff = (size_t)row * 1024 + lane * 16;
        float a0 = 0.f, a1 = 0.f;
#pragma unroll
        for (int q = 0; q < 2; q++) {
#pragma unroll
            for (int e = 0; e < 8; e++) {
                size_t k = q * 8 + e;
                float xf = ldin(x, xoff + k, isf32);
                a0 += xf * ldin(gw, (size_t)lane * 16 + k, isf32);
                a1 += xf * ldin(gw, 1024 + (size_t)lane * 16 + k, isf32);
            }
        }
#pragma unroll
        for (int off = 32; off > 0; off >>= 1) {
            a0 += __shfl_down(a0, off);
            a1 += __shfl_down(a1, off);
        }
        if (lane == 0) {
            gx[row * 2]     = sigf(a0 + ldin(gb, 0, isf32));
            gx[row * 2 + 1] = sigf(a1 + ldin(gb, 1, isf32));
        }
        return;
    }

    int b = blockIdx.x & 7;
    size_t rowbase = (size_t)b * SEQ;

    if (blockIdx.x < 8) {
        // ---------------- GRU (8 waves) ----------------
        __shared__ __align__(16) unsigned short H[2][128];       // flat h, dbuf
        __shared__ __align__(16) unsigned short IH[2][CH][384];  // ih chunk, dbuf (24.6KB)
        int tid = threadIdx.x, lane = tid & 63, w = tid >> 6;    // w in 0..7
        int col = lane & 15, quad = lane >> 4;
        int o = w * 16 + col;                                    // this wave's col
        if (tid < 256) ((unsigned short*)H)[tid] = 0;
        // static B-fragments: g=0(r),1(z),2(n): Whh row g*128+o, k = c*32+quad*8+e
        bf16x8 Bf[3][4];
#pragma unroll
        for (int g = 0; g < 3; g++) {
            int n = g * 128 + o;
#pragma unroll
            for (int c = 0; c < 4; c++) {
                int k0 = c * 32 + quad * 8;
                bf16x8 v;
#pragma unroll
                for (int e = 0; e < 8; e++)
                    v[e] = (short)f2bf(ldin(Whh, (size_t)n * 128 + k0 + e, isf32));
                Bf[g][c] = v;
            }
        }
        float bias_r = ldin(bhh, o, isf32);
        float bias_z = ldin(bhh, 128 + o, isf32);
        float bias_n = ldin(bhh, 256 + o, isf32);
        float hprev = 0.f;
        bool gl = (quad == 0);
        // chunk prologue: chunk0 -> IH[0]; issue chunk1 loads (768 bf16x8/chunk)
        const unsigned short* ihbase = ihw + rowbase * 384;
        bf16x8 stg0, stg1;
        stg0 = *reinterpret_cast<const bf16x8*>(ihbase + (size_t)tid * 8);
        if (tid < 256) stg1 = *reinterpret_cast<const bf16x8*>(ihbase + (size_t)(512 + tid) * 8);
        *reinterpret_cast<bf16x8*>(&IH[0][0][0] + (size_t)tid * 8) = stg0;
        if (tid < 256) *reinterpret_cast<bf16x8*>(&IH[0][0][0] + (size_t)(512 + tid) * 8) = stg1;
        stg0 = *reinterpret_cast<const bf16x8*>(ihbase + (size_t)CH * 384 + (size_t)tid * 8);
        if (tid < 256) stg1 = *reinterpret_cast<const bf16x8*>(ihbase + (size_t)CH * 384 + (size_t)(512 + tid) * 8);
        __syncthreads();

        int p = 0;
        auto gru_step = [&](int t, int cur, int tt) {
            // broadcast A-frags: uniform per quad (4 addrs/wave)
            bf16x8 Af[4];
#pragma unroll
            for (int cc = 0; cc < 4; cc++)
                Af[cc] = *reinterpret_cast<const bf16x8*>(&H[p][cc * 32 + quad * 8]);
            float ir  = bf2f(IH[cur][tt][o]);
            float iz  = bf2f(IH[cur][tt][128 + o]);
            float inn = bf2f(IH[cur][tt][256 + o]);
            // 3 gates x two parallel 2-chains; zf as C-in (no acc zero-init)
            f32x4 aL[3], aH[3];
#pragma unroll
            for (int g = 0; g < 3; g++) {
                aL[g] = __builtin_amdgcn_mfma_f32_16x16x32_bf16(Af[0], Bf[g][0], zf, 0, 0, 0);
                aH[g] = __builtin_amdgcn_mfma_f32_16x16x32_bf16(Af[2], Bf[g][2], zf, 0, 0, 0);
                aL[g] = __builtin_amdgcn_mfma_f32_16x16x32_bf16(Af[1], Bf[g][1], aL[g], 0, 0, 0);
                aH[g] = __builtin_amdgcn_mfma_f32_16x16x32_bf16(Af[3], Bf[g][3], aH[g], 0, 0, 0);
            }
            float sr = aL[0][0] + aH[0][0];
            float sz = aL[1][0] + aH[1][0];
            float sn = aL[2][0] + aH[2][0];
            float r  = sigf(ir + sr + bias_r);
            float zg = sigf(iz + sz + bias_z);
            float n  = tanhf_fast(inn + r * (sn + bias_n));
            float hnew = (1.f - zg) * n + zg * hprev;
            hprev = hnew;
            if (gl) {
                unsigned short hb = f2bf(hnew);
                H[p ^ 1][o] = hb;
                hrw[(rowbase + t) * 128 + o] = hb;
            }
            asm volatile("s_waitcnt lgkmcnt(0)" ::: "memory");
            __builtin_amdgcn_s_barrier();
            asm volatile("" ::: "memory");
            p ^= 1;
        };

        for (int c = 0; c < NCH; c++) {
            int cur = c & 1;
            for (int tt = 0; tt < 8; tt++) gru_step(c * CH + tt, cur, tt);
            // mid-chunk staging: write chunk c+1 (loaded ~CH steps ago),
            // issue chunk c+2 loads — drains at next step's barrier
            if (c + 1 < NCH) {
                unsigned short* dst = &IH[(c + 1) & 1][0][0];
                *reinterpret_cast<bf16x8*>(dst + (size_t)tid * 8) = stg0;
                if (tid < 256) *reinterpret_cast<bf16x8*>(dst + (size_t)(512 + tid) * 8) = stg1;
                if (c + 2 < NCH) {
                    const unsigned short* src = ihbase + (size_t)(c + 2) * CH * 384;
                    stg0 = *reinterpret_cast<const bf16x8*>(src + (size_t)tid * 8);
                    if (tid < 256) stg1 = *reinterpret_cast<const bf16x8*>(src + (size_t)(512 + tid) * 8);
                }
            }
            for (int tt = 8; tt < CH; tt++) gru_step(c * CH + tt, cur, tt);
        }
    } else {
        // ---------------- SSM (wave 0 only) ----------------
        if (threadIdx.x >= 64) return;
        int lane = threadIdx.x, col = lane & 15, quad = lane >> 4;
        __shared__ __align__(16) unsigned short Hs[2][64];       // flat h, dbuf
        __shared__ __align__(16) unsigned short BX[2][CH][64];   // bx chunk, dbuf (4KB)
        ((unsigned short*)Hs)[lane] = 0;
        ((unsigned short*)Hs)[64 + lane] = 0;
        bf16x8 Bf[4][2];
#pragma unroll
        for (int l = 0; l < 4; l++) {
            int n = l * 16 + col;
#pragma unroll
            for (int c = 0; c < 2; c++) {
                int k0 = c * 32 + quad * 8;
                bf16x8 v;
#pragma unroll
                for (int e = 0; e < 8; e++)
                    v[e] = (short)f2bf(ldin(Amat, (size_t)n * 64 + k0 + e, isf32));
                Bf[l][c] = v;
            }
        }
        bool gl = (quad == 0);
        const unsigned short* bxbase = bxw + rowbase * 64;
        bf16x8 stg[2];
#pragma unroll
        for (int q = 0; q < 2; q++)
            stg[q] = *reinterpret_cast<const bf16x8*>(bxbase + (size_t)(q * 64 + lane) * 8);
#pragma unroll
        for (int q = 0; q < 2; q++)
            *reinterpret_cast<bf16x8*>(&BX[0][0][0] + (size_t)(q * 64 + lane) * 8) = stg[q];
#pragma unroll
        for (int q = 0; q < 2; q++)
            stg[q] = *reinterpret_cast<const bf16x8*>(bxbase + (size_t)CH * 64 + (size_t)(q * 64 + lane) * 8);
        asm volatile("s_waitcnt lgkmcnt(0)" ::: "memory");

        int p = 0;
        auto ssm_step = [&](int t, int cur, int tt) {
            bf16x8 Af[2];
#pragma unroll
            for (int cc = 0; cc < 2; cc++)
                Af[cc] = *reinterpret_cast<const bf16x8*>(&Hs[p][cc * 32 + quad * 8]);
            float bx[4];
#pragma unroll
            for (int l = 0; l < 4; l++) bx[l] = bf2f(BX[cur][tt][l * 16 + col]);
            f32x4 acc[4];
#pragma unroll
            for (int l = 0; l < 4; l++) {
                acc[l] = __builtin_amdgcn_mfma_f32_16x16x32_bf16(Af[0], Bf[l][0], zf, 0, 0, 0);
                acc[l] = __builtin_amdgcn_mfma_f32_16x16x32_bf16(Af[1], Bf[l][1], acc[l], 0, 0, 0);
            }
#pragma unroll
            for (int l = 0; l < 4; l++) {
                int o = l * 16 + col;
                float v = acc[l][0] + bx[l];
                float hv = v * sigf(v);
                unsigned short hb = f2bf(hv);
                if (gl) {
                    Hs[p ^ 1][o] = hb;
                    hsw[(rowbase + t) * 64 + o] = hb;
                }
            }
            asm volatile("s_waitcnt lgkmcnt(0)" ::: "memory");
            p ^= 1;
        };

        for (int c = 0; c < NCH; c++) {
            int cur = c & 1;
            for (int tt = 0; tt < 8; tt++) ssm_step(c * CH + tt, cur, tt);
            if (c + 1 < NCH) {
                unsigned short* dst = &BX[(c + 1) & 1][0][0];
#pragma unroll
                for (int q = 0; q < 2; q++)
                    *reinterpret_cast<bf16x8*>(dst + (size_t)(q * 64 + lane) * 8) = stg[q];
                if (c + 2 < NCH) {
#pragma unroll
                    for (int q = 0; q < 2; q++)
                        stg[q] = *reinterpret_cast<const bf16x8*>(
                            bxbase + (size_t)(c + 2) * CH * 64 + (size_t)(q * 64 + lane) * 8);
                }
            }
            for (int tt = 8; tt < CH; tt++) ssm_step(c * CH + tt, cur, tt);
        }
    }
}

// out[row,col] = g0*(x.Dw^T + hs.Cw^T + Cb + Db) + g1*(hr.pw^T + pb) — f32 store
__global__ __launch_bounds__(256) void out_kernel(
    const void* __restrict__ x,  const void* __restrict__ Dw, const void* __restrict__ Db,
    const unsigned short* __restrict__ hs, const void* __restrict__ Cw, const void* __restrict__ Cb,
    const unsigned short* __restrict__ hr, const void* __restrict__ pw, const void* __restrict__ pb,
    const float* __restrict__ gx, float* __restrict__ out,
    const int* __restrict__ flagp) {
    __shared__ __align__(16) short As[128][40];
    __shared__ __align__(16) short Bs[128][40];
    int isf32 = *flagp;
    int tid = threadIdx.x, lane = tid & 63, wave = tid >> 6;
    int wm = (wave >> 1) << 6, wn = (wave & 1) << 6;
    int tileM = blockIdx.x << 7, tileN = blockIdx.y << 7;
    f32x4 z = {0.f, 0.f, 0.f, 0.f};
    f32x4 acc1[4][4], acc2[4][4];
#pragma unroll
    for (int i = 0; i < 4; i++)
#pragma unroll
        for (int j = 0; j < 4; j++) { acc1[i][j] = z; acc2[i][j] = z; }

    for (int kb = 0; kb < 1024; kb += 32) {        // x . Dw^T
        __syncthreads();
        stage_tile(x,  1024, tileM, MROWS - 1, kb, As, tid, isf32);
        stage_tile(Dw, 1024, tileN, 1023, kb, Bs, tid, isf32);
        __syncthreads();
        mfma_tiles(As, Bs, wm, wn, lane, acc1);
    }
    for (int kb = 0; kb < 64; kb += 32) {          // + hs . Cw^T, same acc
        __syncthreads();
        stage_tile(hs, 64, tileM, MROWS - 1, kb, As, tid, 0);
        stage_tile(Cw, 64, tileN, 1023, kb, Bs, tid, isf32);
        __syncthreads();
        mfma_tiles(As, Bs, wm, wn, lane, acc1);
    }
    for (int kb = 0; kb < 128; kb += 32) {         // hr . pw^T
        __syncthreads();
        stage_tile(hr, 128, tileM, MROWS - 1, kb, As, tid, 0);
        stage_tile(pw, 128, tileN, 1023, kb, Bs, tid, isf32);
        __syncthreads();
        mfma_tiles(As, Bs, wm, wn, lane, acc2);
    }
#pragma unroll
    for (int i = 0; i < 4; i++) {
        int r0 = tileM + wm + i * 16 + ((lane >> 4) << 2);
#pragma unroll
        for (int j = 0; j < 4; j++) {
            int col = tileN + wn + j * 16 + (lane & 15);
            float cb  = ldin(Cb, col, isf32) + ldin(Db, col, isf32);
            float pbv = ldin(pb, col, isf32);
#pragma unroll
            for (int r = 0; r < 4; r++) {
                int row = r0 + r;
                float g0 = gx[row * 2], g1 = gx[row * 2 + 1];
                out[(size_t)row * 1024 + col] =
                    g0 * (acc1[i][j][r] + cb) + g1 * (acc2[i][j][r] + pbv);
            }
        }
    }
}

extern "C" void kernel_launch(void* const* d_in, const int* in_sizes, int n_in,
                              void* d_out, int out_size, void* d_ws, size_t ws_size,
                              hipStream_t stream) {
    static const int expect_sizes[16] = {16777216, 4096, 65536, 64, 65536, 1024,
                                         1048576, 1024, 393216, 384, 49152, 384,
                                         131072, 1024, 2048, 2};
    bool order_ok = (n_in == 16);
    if (order_ok)
        for (int i = 0; i < 16; i++)
            if (in_sizes[i] != expect_sizes[i]) { order_ok = false; break; }
    float* out = (float*)d_out;
    if (!order_ok) {
        zero_out_kernel<<<dim3(4096), dim3(256), 0, stream>>>(out);
        return;
    }

    const void* x    = d_in[0];
    const void* Amat = d_in[1];
    const void* Bw   = d_in[2];
    const void* Bb   = d_in[3];
    const void* Cw   = d_in[4];
    const void* Cb   = d_in[5];
    const void* Dw   = d_in[6];
    const void* Db   = d_in[7];
    const void* Wih  = d_in[8];
    const void* bih  = d_in[9];
    const void* Whh  = d_in[10];
    const void* bhh  = d_in[11];
    const void* pw   = d_in[12];
    const void* pb   = d_in[13];
    const void* gw   = d_in[14];
    const void* gb   = d_in[15];

    // d_ws base (21.1 MB): flag | gx | hs | hr | bx | ih ; then optional bf16 mirrors
    char* ws = (char*)d_ws;
    int*            flg = (int*)(ws);                        //       256 B (flg[0]=sniff, flg[1]=0)
    float*          gxw = (float*)(ws + 256);                //   131,072 B
    unsigned short* hsw = (unsigned short*)(ws + 131328);    // 2,097,152 B
    unsigned short* hrw = (unsigned short*)(ws + 2228480);   // 4,194,304 B
    unsigned short* bxw = (unsigned short*)(ws + 6422784);   // 2,097,152 B
    unsigned short* ihw = (unsigned short*)(ws + 8519936);   // 12,582,912 B
    // bf16 mirrors (ws-gated)
    unsigned short* xb   = (unsigned short*)(ws + 21102848); // 33,554,432 B
    unsigned short* Dwb  = (unsigned short*)(ws + 54657280); //  2,097,152 B
    unsigned short* Wihb = (unsigned short*)(ws + 56754432); //    786,432 B
    unsigned short* pwb  = (unsigned short*)(ws + 57540864); //    262,144 B
    unsigned short* Cwb  = (unsigned short*)(ws + 57803008); //    131,072 B
    unsigned short* Bwb  = (unsigned short*)(ws + 57934080); //    131,072 B
    unsigned short* bihb = (unsigned short*)(ws + 58065152); //        768 B (4KB slot)
    unsigned short* Bbb  = (unsigned short*)(ws + 58069248);
    unsigned short* Cbb  = (unsigned short*)(ws + 58073344);
    unsigned short* Dbb  = (unsigned short*)(ws + 58077440);
    unsigned short* pbb  = (unsigned short*)(ws + 58081536);
    bool big = ws_size >= 58085632ull;

    dim3 blk(256);
    sniff_kernel<<<dim3(1), dim3(64), 0, stream>>>((const unsigned short*)x, flg);
    if (big) {
        cvt_all_kernel<<<dim3(4513), blk, 0, stream>>>(
            x, Dw, Wih, pw, Cw, Bw, bih, Bb, Cb, Db, pb,
            xb, Dwb, Wihb, pwb, Cwb, Bwb, bihb, Bbb, Cbb, Dbb, pbb, flg);
        gemm_fused_kernel<<<dim3(128, 4), blk, 0, stream>>>(
            xb, Wihb, bihb, ihw, Bwb, Bbb, bxw, flg + 1);
        scan_kernel<<<dim3(2064), dim3(512), 0, stream>>>(
            Amat, Whh, bhh, bxw, ihw, hsw, hrw, x, gw, gb, gxw, flg);
        out_kernel<<<dim3(128, 8), blk, 0, stream>>>(
            xb, Dwb, Dbb, hsw, Cwb, Cbb, hrw, pwb, pbb, gxw, out, flg + 1);
    } else {
        gemm_fused_kernel<<<dim3(128, 4), blk, 0, stream>>>(
            x, Wih, bih, ihw, Bw, Bb, bxw, flg);
        scan_kernel<<<dim3(2064), dim3(512), 0, stream>>>(
            Amat, Whh, bhh, bxw, ihw, hsw, hrw, x, gw, gb, gxw, flg);
        out_kernel<<<dim3(128, 8), blk, 0, stream>>>(
            x, Dw, Db, hsw, Cw, Cb, hrw, pw, pb, gxw, out, flg);
    }
}